// Round 1
// baseline (2890.264 us; speedup 1.0000x reference)
//
#include <hip/hip_runtime.h>
#include <cstdint>

// 1 = modern JAX (jax_threefry_partitionable=True, default since 0.4.30)
// 0 = legacy threefry counter layout
#define RNG_PARTITIONABLE 1

#define MAXG 512

// ---------------- Threefry-2x32 (exact JAX schedule) ----------------
__host__ __device__ inline void tf2x32(uint32_t k0, uint32_t k1,
                                       uint32_t x0, uint32_t x1,
                                       uint32_t& o0, uint32_t& o1) {
  const uint32_t k2 = k0 ^ k1 ^ 0x1BD11BDAu;
#define ROT(v, r) (((v) << (r)) | ((v) >> (32 - (r))))
#define R4(a,b,c,d) \
  x0 += x1; x1 = ROT(x1, a); x1 ^= x0; \
  x0 += x1; x1 = ROT(x1, b); x1 ^= x0; \
  x0 += x1; x1 = ROT(x1, c); x1 ^= x0; \
  x0 += x1; x1 = ROT(x1, d); x1 ^= x0;
  x0 += k0; x1 += k1;
  R4(13,15,26,6)   x0 += k1; x1 += k2 + 1u;
  R4(17,29,16,24)  x0 += k2; x1 += k0 + 2u;
  R4(13,15,26,6)   x0 += k0; x1 += k1 + 3u;
  R4(17,29,16,24)  x0 += k1; x1 += k2 + 4u;
  R4(13,15,26,6)   x0 += k2; x1 += k0 + 5u;
  o0 = x0; o1 = x1;
#undef R4
#undef ROT
}

// ---------------- exact (contraction-free, IEEE) IoU ----------------
__device__ __forceinline__ float iou_fn(float ax0, float ay0, float ax1, float ay1,
                                        float g0, float g1, float g2, float g3,
                                        float area_a, float area_g) {
  float ix0 = fmaxf(ax0, g0);
  float iy0 = fmaxf(ay0, g1);
  float ix1 = fminf(ax1, g2);
  float iy1 = fminf(ay1, g3);
  float iw = fmaxf(__fsub_rn(ix1, ix0), 0.0f);
  float ih = fmaxf(__fsub_rn(iy1, iy0), 0.0f);
  float inter = __fmul_rn(iw, ih);
  float denom = __fadd_rn(__fsub_rn(__fadd_rn(area_a, area_g), inter), 1e-5f);
  return __fdiv_rn(inter, denom);
}

__device__ __forceinline__ float area_fn(float x0, float y0, float x1, float y1) {
  return __fmul_rn(fmaxf(__fsub_rn(x1, x0), 0.0f), fmaxf(__fsub_rn(y1, y0), 0.0f));
}

// ---------------- K0: init scratch state ----------------
__global__ void k0_init(int* gt_max, int* counters, int* hist, int G) {
  int i = blockIdx.x * blockDim.x + threadIdx.x;
  if (i < G) gt_max[i] = 0xBF800000;  // bits of -1.0f
  if (i < 2) counters[i] = 0;
  int stride = gridDim.x * blockDim.x;
  for (int b = i; b < 2 * 16384; b += stride) hist[b] = 0;
}

// ---------------- K1: per-anchor max/argmax + per-gt max ----------------
__global__ void k1_iou(const float4* __restrict__ anch, const float* __restrict__ gt,
                       const float* __restrict__ info, float* __restrict__ maxov,
                       int* __restrict__ meta, int* __restrict__ gt_max,
                       int N, int G) {
  __shared__ float4 sg[MAXG];
  __shared__ float sarea[MAXG];
  __shared__ int smax[MAXG];
  for (int t = threadIdx.x; t < G; t += blockDim.x) {
    float g0 = gt[5*t], g1 = gt[5*t+1], g2 = gt[5*t+2], g3 = gt[5*t+3];
    sg[t] = make_float4(g0, g1, g2, g3);
    sarea[t] = area_fn(g0, g1, g2, g3);
    smax[t] = 0xBF800000;
  }
  __syncthreads();
  const float H = info[0], W = info[1];
  int i = blockIdx.x * blockDim.x + threadIdx.x;
  if (i < N) {
    float4 a = anch[i];
    bool inside = (a.x >= 0.0f) && (a.y >= 0.0f) && (a.z < W) && (a.w < H);
    float area_a = area_fn(a.x, a.y, a.z, a.w);
    float best = -INFINITY; int bj = 0;
    for (int j = 0; j < G; ++j) {
      float4 g = sg[j];
      float iou = iou_fn(a.x, a.y, a.z, a.w, g.x, g.y, g.z, g.w, area_a, sarea[j]);
      float mval = inside ? iou : -1.0f;
      if (mval > best) { best = mval; bj = j; }   // strict > keeps FIRST argmax
      if (inside) atomicMax(&smax[j], __float_as_int(iou));  // values >= 0: int order == float order
    }
    maxov[i] = best;
    meta[i] = bj | (inside ? (1 << 9) : 0);
  }
  __syncthreads();
  for (int t = threadIdx.x; t < G; t += blockDim.x)
    atomicMax(&gt_max[t], smax[t]);
}

// ---------------- K2: labels + rng mantissas + counts ----------------
__global__ void k2_label(const float4* __restrict__ anch, const float* __restrict__ gt,
                         const float* __restrict__ maxov, int* __restrict__ meta,
                         const int* __restrict__ gt_max, unsigned* __restrict__ marr,
                         int* __restrict__ counters,
                         uint32_t kf0, uint32_t kf1, uint32_t kb0, uint32_t kb1,
                         int N, int G) {
  __shared__ float4 sg[MAXG];
  __shared__ float sarea[MAXG];
  __shared__ float sgm[MAXG];
  for (int t = threadIdx.x; t < G; t += blockDim.x) {
    float g0 = gt[5*t], g1 = gt[5*t+1], g2 = gt[5*t+2], g3 = gt[5*t+3];
    sg[t] = make_float4(g0, g1, g2, g3);
    sarea[t] = area_fn(g0, g1, g2, g3);
    sgm[t] = __int_as_float(gt_max[t]);
  }
  __syncthreads();
  int i = blockIdx.x * blockDim.x + threadIdx.x;
  if (i >= N) return;
  int mt = meta[i];
  bool inside = (mt >> 9) & 1;
  int lab = -1;
  if (inside) {
    float4 a = anch[i];
    float area_a = area_fn(a.x, a.y, a.z, a.w);
    bool best = false;
    for (int j = 0; j < G; ++j) {
      float4 g = sg[j];
      float iou = iou_fn(a.x, a.y, a.z, a.w, g.x, g.y, g.z, g.w, area_a, sarea[j]);
      best = best || (iou == sgm[j]);
    }
    float mo = maxov[i];
    if (best) lab = 1;          // exact reference order of the four where()s
    if (mo >= 0.7f) lab = 1;
    if (mo < 0.3f) lab = 0;
  }
  if (lab == 1) atomicAdd(&counters[0], 1);
  else if (lab == 0) atomicAdd(&counters[1], 1);
  unsigned m = 0;
  if (lab >= 0) {
    uint32_t K0 = lab ? kf0 : kb0;
    uint32_t K1v = lab ? kf1 : kb1;
    uint32_t o0, o1;
#if RNG_PARTITIONABLE
    tf2x32(K0, K1v, 0u, (uint32_t)i, o0, o1);
    m = (o0 ^ o1) >> 9;               // uniform mantissa, 23 bits
#else
    int NH = N >> 1;
    if (i < NH) { tf2x32(K0, K1v, (uint32_t)i, (uint32_t)(i + NH), o0, o1); m = o0 >> 9; }
    else        { tf2x32(K0, K1v, (uint32_t)(i - NH), (uint32_t)i, o0, o1); m = o1 >> 9; }
#endif
  }
  marr[i] = m;
  meta[i] = (mt & 0x3FF) | ((lab + 1) << 10);
}

// ---------------- selection: 3-level radix histogram over 42-bit keys ----------------
// key = (m << 19) | anchor_index  (distinct; matches stable argsort by (value, index))
__global__ void khist(const int* __restrict__ meta, const unsigned* __restrict__ marr,
                      const unsigned long long* __restrict__ prefix,
                      const int* __restrict__ Karr, int* __restrict__ hist,
                      int level, int N) {
  int stride = gridDim.x * blockDim.x;
  for (int i = blockIdx.x * blockDim.x + threadIdx.x; i < N; i += stride) {
    int lab = ((meta[i] >> 10) & 3) - 1;
    if (lab < 0) continue;
    int s = lab ? 0 : 1;                      // 0 = fg selection, 1 = bg selection
    if (level > 0 && Karr[s] <= 0) continue;
    unsigned long long key = ((unsigned long long)marr[i] << 19) | (unsigned)i;
    int bin;
    if (level == 0) bin = (int)(key >> 28);
    else if (level == 1) {
      if ((key >> 28) != prefix[s]) continue;
      bin = (int)((key >> 14) & 0x3FFF);
    } else {
      if ((key >> 14) != prefix[s]) continue;
      bin = (int)(key & 0x3FFF);
    }
    atomicAdd(&hist[s * 16384 + bin], 1);
  }
}

__global__ void kfind(int* hist, const int* counters, int* Karr,
                      unsigned long long* prefix, unsigned long long* thr,
                      int level) {
  __shared__ int part[256];
  __shared__ int s_selt, s_selk;
  int t = threadIdx.x;
  for (int s = 0; s < 2; ++s) {
    int K;
    if (level == 0) {
      int fgc = counters[0], bgc = counters[1];
      int fgk = min(fgc, 128);
      K = (s == 0) ? fgk : min(256 - fgk, bgc);
      if (t == 0) {
        Karr[s] = K;
        prefix[s] = 0ull;
        if (K <= 0) thr[s] = 0ull;   // keep nothing
      }
    } else {
      K = Karr[s];
    }
    __syncthreads();
    if (K > 0) {                       // K uniform across block
      const int base = s * 16384;
      int sum = 0;
      for (int b = 0; b < 64; ++b) sum += hist[base + t * 64 + b];
      part[t] = sum;
      __syncthreads();
      if (t == 0) {
        int cum = 0; s_selt = 0; s_selk = K;
        for (int q = 0; q < 256; ++q) {
          if (cum + part[q] >= K) { s_selt = q; s_selk = K - cum; break; }
          cum += part[q];
        }
      }
      __syncthreads();
      if (t == s_selt) {
        int cum = 0, Kc = s_selk;
        for (int b = 0; b < 64; ++b) {
          int h = hist[base + t * 64 + b];
          if (cum + h >= Kc) {
            Karr[s] = Kc - cum;        // remaining rank inside this bin
            unsigned long long p = (prefix[s] << 14) | (unsigned long long)(t * 64 + b);
            prefix[s] = p;
            if (level == 2) thr[s] = p + 1ull;   // keep iff key < thr
            break;
          }
          cum += h;
        }
      }
      __syncthreads();
    }
    for (int b = t; b < 16384; b += 256) hist[s * 16384 + b] = 0;  // ready for next level
    __syncthreads();
  }
}

// ---------------- K3: final labels / targets / weights ----------------
__global__ void k3_out(const float4* __restrict__ anch, const float* __restrict__ gt,
                       const int* __restrict__ meta, const unsigned* __restrict__ marr,
                       const int* __restrict__ counters,
                       const unsigned long long* __restrict__ thr,
                       float* __restrict__ out, int N) {
  int i = blockIdx.x * blockDim.x + threadIdx.x;
  if (i >= N) return;
  int mt = meta[i];
  int lab = ((mt >> 10) & 3) - 1;
  bool inside = (mt >> 9) & 1;
  int am = mt & 0x1FF;
  if (lab >= 0) {
    int s = lab ? 0 : 1;
    unsigned long long key = ((unsigned long long)marr[i] << 19) | (unsigned)i;
    if (key >= thr[s]) lab = -1;
  }
  int fgc = counters[0], bgc = counters[1];
  int fgk = min(fgc, 128);
  int ne = fgk + min(256 - fgk, bgc);   // num_examples after both subsamples
  out[i] = (float)lab;
  float4 tg = make_float4(0.0f, 0.0f, 0.0f, 0.0f);
  if (inside) {
    float4 a = anch[i];
    float g0 = gt[5*am], g1 = gt[5*am+1], g2 = gt[5*am+2], g3 = gt[5*am+3];
    float ew = __fadd_rn(__fsub_rn(a.z, a.x), 1.0f);
    float eh = __fadd_rn(__fsub_rn(a.w, a.y), 1.0f);
    float ecx = __fadd_rn(a.x, __fmul_rn(0.5f, ew));
    float ecy = __fadd_rn(a.y, __fmul_rn(0.5f, eh));
    float gw = __fadd_rn(__fsub_rn(g2, g0), 1.0f);
    float gh = __fadd_rn(__fsub_rn(g3, g1), 1.0f);
    float gcx = __fadd_rn(g0, __fmul_rn(0.5f, gw));
    float gcy = __fadd_rn(g1, __fmul_rn(0.5f, gh));
    tg = make_float4(__fdiv_rn(__fsub_rn(gcx, ecx), ew),
                     __fdiv_rn(__fsub_rn(gcy, ecy), eh),
                     logf(__fdiv_rn(gw, ew)),
                     logf(__fdiv_rn(gh, eh)));
  }
  reinterpret_cast<float4*>(out + (size_t)N)[i] = tg;
  float bw = (lab == 1) ? 1.0f : 0.0f;
  reinterpret_cast<float4*>(out + 5 * (size_t)N)[i] = make_float4(bw, bw, bw, bw);
  float ov = (lab >= 0) ? __fdiv_rn(1.0f, (float)ne) : 0.0f;
  reinterpret_cast<float4*>(out + 9 * (size_t)N)[i] = make_float4(ov, ov, ov, ov);
}

// ---------------- launch ----------------
extern "C" void kernel_launch(void* const* d_in, const int* in_sizes, int n_in,
                              void* d_out, int out_size, void* d_ws, size_t ws_size,
                              hipStream_t stream) {
  const float4* anch = (const float4*)d_in[3];
  const float* gt    = (const float*)d_in[1];
  const float* info  = (const float*)d_in[2];
  float* out = (float*)d_out;
  const int N = in_sizes[3] / 4;       // 331776  (< 2^19, required by key packing)
  const int G = in_sizes[1] / 5;       // 128

  char* ws = (char*)d_ws;
  int* gt_max                 = (int*)(ws + 0);        // 512 ints max
  int* counters               = (int*)(ws + 2048);     // fg, bg
  int* Karr                   = (int*)(ws + 2112);
  unsigned long long* prefix  = (unsigned long long*)(ws + 2176);
  unsigned long long* thr     = (unsigned long long*)(ws + 2240);
  int* hist                   = (int*)(ws + 4096);     // 2 * 16384 ints
  float* maxov                = (float*)(ws + 135168);
  int* meta                   = (int*)(ws + 135168 + 4 * (size_t)N);
  unsigned* marr              = (unsigned*)(ws + 135168 + 8 * (size_t)N);

  // host-side key derivation: kf, kb = split(key(42))
  uint32_t kf0, kf1, kb0, kb1;
#if RNG_PARTITIONABLE
  tf2x32(0u, 42u, 0u, 0u, kf0, kf1);
  tf2x32(0u, 42u, 0u, 1u, kb0, kb1);
#else
  {
    uint32_t a0, a1, b0, b1;
    tf2x32(0u, 42u, 0u, 2u, a0, a1);   // block (0,2) -> (r00, r01)
    tf2x32(0u, 42u, 1u, 3u, b0, b1);   // block (1,3) -> (r10, r11)
    kf0 = a0; kf1 = b0; kb0 = a1; kb1 = b1;
  }
#endif

  const int NB = (N + 255) / 256;
  k0_init<<<130, 256, 0, stream>>>(gt_max, counters, hist, G);
  k1_iou<<<NB, 256, 0, stream>>>(anch, gt, info, maxov, meta, gt_max, N, G);
  k2_label<<<NB, 256, 0, stream>>>(anch, gt, maxov, meta, gt_max, marr, counters,
                                   kf0, kf1, kb0, kb1, N, G);
  for (int lvl = 0; lvl < 3; ++lvl) {
    khist<<<256, 256, 0, stream>>>(meta, marr, prefix, Karr, hist, lvl, N);
    kfind<<<1, 256, 0, stream>>>(hist, counters, Karr, prefix, thr, lvl);
  }
  k3_out<<<NB, 256, 0, stream>>>(anch, gt, meta, marr, counters, thr, out, N);
}

// Round 2
// 218.615 us; speedup vs baseline: 13.2208x; 13.2208x over previous
//
#include <hip/hip_runtime.h>
#include <cstdint>

// 1 = modern JAX (jax_threefry_partitionable=True, default since 0.4.30)
#define RNG_PARTITIONABLE 1

#define MAXG 512

// ---------------- Threefry-2x32 (exact JAX schedule) ----------------
__host__ __device__ inline void tf2x32(uint32_t k0, uint32_t k1,
                                       uint32_t x0, uint32_t x1,
                                       uint32_t& o0, uint32_t& o1) {
  const uint32_t k2 = k0 ^ k1 ^ 0x1BD11BDAu;
#define ROT(v, r) (((v) << (r)) | ((v) >> (32 - (r))))
#define R4(a,b,c,d) \
  x0 += x1; x1 = ROT(x1, a); x1 ^= x0; \
  x0 += x1; x1 = ROT(x1, b); x1 ^= x0; \
  x0 += x1; x1 = ROT(x1, c); x1 ^= x0; \
  x0 += x1; x1 = ROT(x1, d); x1 ^= x0;
  x0 += k0; x1 += k1;
  R4(13,15,26,6)   x0 += k1; x1 += k2 + 1u;
  R4(17,29,16,24)  x0 += k2; x1 += k0 + 2u;
  R4(13,15,26,6)   x0 += k0; x1 += k1 + 3u;
  R4(17,29,16,24)  x0 += k1; x1 += k2 + 4u;
  R4(13,15,26,6)   x0 += k2; x1 += k0 + 5u;
  o0 = x0; o1 = x1;
#undef R4
#undef ROT
}

// ---------------- exact (contraction-free, IEEE) IoU ----------------
__device__ __forceinline__ float iou_fn(float ax0, float ay0, float ax1, float ay1,
                                        float g0, float g1, float g2, float g3,
                                        float area_a, float area_g) {
  float ix0 = fmaxf(ax0, g0);
  float iy0 = fmaxf(ay0, g1);
  float ix1 = fminf(ax1, g2);
  float iy1 = fminf(ay1, g3);
  float iw = fmaxf(__fsub_rn(ix1, ix0), 0.0f);
  float ih = fmaxf(__fsub_rn(iy1, iy0), 0.0f);
  float inter = __fmul_rn(iw, ih);
  float denom = __fadd_rn(__fsub_rn(__fadd_rn(area_a, area_g), inter), 1e-5f);
  return __fdiv_rn(inter, denom);
}

__device__ __forceinline__ float area_fn(float x0, float y0, float x1, float y1) {
  return __fmul_rn(fmaxf(__fsub_rn(x1, x0), 0.0f), fmaxf(__fsub_rn(y1, y0), 0.0f));
}

// ---------------- K0: init scratch state ----------------
__global__ void k0_init(int* gt_max, int* counters, int* hist, int G) {
  int i = blockIdx.x * blockDim.x + threadIdx.x;
  if (i < G) gt_max[i] = 0xBF800000;  // bits of -1.0f
  if (i < 2) counters[i] = 0;
  int stride = gridDim.x * blockDim.x;
  for (int b = i; b < 2 * 16384; b += stride) hist[b] = 0;
}

// ---------------- K1: per-anchor max/argmax + per-gt max ----------------
__global__ void k1_iou(const float4* __restrict__ anch, const float* __restrict__ gt,
                       const float* __restrict__ info, float* __restrict__ maxov,
                       int* __restrict__ meta, int* __restrict__ gt_max,
                       int N, int G) {
  __shared__ float4 sg[MAXG];
  __shared__ float sarea[MAXG];
  __shared__ int smax[MAXG];
  for (int t = threadIdx.x; t < G; t += blockDim.x) {
    float g0 = gt[5*t], g1 = gt[5*t+1], g2 = gt[5*t+2], g3 = gt[5*t+3];
    sg[t] = make_float4(g0, g1, g2, g3);
    sarea[t] = area_fn(g0, g1, g2, g3);
    smax[t] = 0xBF800000;
  }
  __syncthreads();
  const float H = info[0], W = info[1];
  int i = blockIdx.x * blockDim.x + threadIdx.x;
  float4 a = make_float4(0.f, 0.f, 0.f, 0.f);
  bool inside = false;
  float area_a = 0.f;
  if (i < N) {
    a = anch[i];
    inside = (a.x >= 0.0f) && (a.y >= 0.0f) && (a.z < W) && (a.w < H);
    area_a = area_fn(a.x, a.y, a.z, a.w);
  }
  float best = -INFINITY; int bj = 0;
  const int lane0 = ((threadIdx.x & 63) == 0);
  #pragma unroll 2
  for (int j = 0; j < G; ++j) {
    float4 g = sg[j];
    float iou = iou_fn(a.x, a.y, a.z, a.w, g.x, g.y, g.z, g.w, area_a, sarea[j]);
    float mval = inside ? iou : -1.0f;
    if (mval > best) { best = mval; bj = j; }   // strict > keeps FIRST argmax
    // exact wave-wide fmax reduce (associative, order-independent)
    float w = mval;
    w = fmaxf(w, __shfl_xor(w, 32));
    w = fmaxf(w, __shfl_xor(w, 16));
    w = fmaxf(w, __shfl_xor(w, 8));
    w = fmaxf(w, __shfl_xor(w, 4));
    w = fmaxf(w, __shfl_xor(w, 2));
    w = fmaxf(w, __shfl_xor(w, 1));
    if (lane0) atomicMax(&smax[j], __float_as_int(w));  // values >= -1.0 handled: nonneg int order == float order, 0xBF800000 < 0
  }
  if (i < N) {
    maxov[i] = best;
    meta[i] = bj | (inside ? (1 << 9) : 0);
  }
  __syncthreads();
  for (int t = threadIdx.x; t < G; t += blockDim.x)
    atomicMax(&gt_max[t], smax[t]);
}

// ---------------- K2: labels + rng mantissas + counts ----------------
__global__ void k2_label(const float4* __restrict__ anch, const float* __restrict__ gt,
                         const float* __restrict__ maxov, int* __restrict__ meta,
                         const int* __restrict__ gt_max, unsigned* __restrict__ marr,
                         int* __restrict__ counters,
                         uint32_t kf0, uint32_t kf1, uint32_t kb0, uint32_t kb1,
                         int N, int G) {
  __shared__ float4 sg[MAXG];
  __shared__ float sarea[MAXG];
  __shared__ float sgm[MAXG];
  __shared__ int cnt_s[2];
  if (threadIdx.x < 2) cnt_s[threadIdx.x] = 0;
  for (int t = threadIdx.x; t < G; t += blockDim.x) {
    float g0 = gt[5*t], g1 = gt[5*t+1], g2 = gt[5*t+2], g3 = gt[5*t+3];
    sg[t] = make_float4(g0, g1, g2, g3);
    sarea[t] = area_fn(g0, g1, g2, g3);
    sgm[t] = __int_as_float(gt_max[t]);
  }
  __syncthreads();
  int i = blockIdx.x * blockDim.x + threadIdx.x;
  int mt = 0;
  bool inside = false;
  float mo = -1.0f;
  if (i < N) {
    mt = meta[i];
    inside = (mt >> 9) & 1;
    mo = maxov[i];
  }
  // label only depends on is_gt_best when 0.3 <= mo < 0.7 (the <0.3 where()
  // overrides is_gt_best; >=0.7 sets 1 anyway). Skip the 128-IoU loop otherwise.
  bool need = inside && (mo >= 0.3f) && (mo < 0.7f);
  bool gbest = false;
  if (__any(need)) {
    float4 a = make_float4(0.f, 0.f, 0.f, 0.f);
    float area_a = 0.f;
    if (i < N) { a = anch[i]; area_a = area_fn(a.x, a.y, a.z, a.w); }
    #pragma unroll 4
    for (int j = 0; j < G; ++j) {
      float4 g = sg[j];
      float iou = iou_fn(a.x, a.y, a.z, a.w, g.x, g.y, g.z, g.w, area_a, sarea[j]);
      gbest = gbest | (iou == sgm[j]);
    }
  }
  int lab = -1;
  if (inside) {
    if (mo < 0.3f)       lab = 0;
    else if (mo >= 0.7f) lab = 1;
    else                 lab = gbest ? 1 : -1;
  }
  // block-level counting: ballot -> popcount -> 1 LDS add per wave -> 1 global atomic per block
  unsigned long long bf = __ballot(lab == 1);
  unsigned long long bb = __ballot(lab == 0);
  if ((threadIdx.x & 63) == 0) {
    if (bf) atomicAdd(&cnt_s[0], __popcll(bf));
    if (bb) atomicAdd(&cnt_s[1], __popcll(bb));
  }
  __syncthreads();
  if (threadIdx.x == 0) {
    if (cnt_s[0]) atomicAdd(&counters[0], cnt_s[0]);
    if (cnt_s[1]) atomicAdd(&counters[1], cnt_s[1]);
  }
  if (i >= N) return;
  unsigned m = 0;
  if (lab >= 0) {
    uint32_t K0 = lab ? kf0 : kb0;
    uint32_t K1v = lab ? kf1 : kb1;
    uint32_t o0, o1;
#if RNG_PARTITIONABLE
    tf2x32(K0, K1v, 0u, (uint32_t)i, o0, o1);
    m = (o0 ^ o1) >> 9;               // uniform mantissa, 23 bits
#else
    int NH = N >> 1;
    if (i < NH) { tf2x32(K0, K1v, (uint32_t)i, (uint32_t)(i + NH), o0, o1); m = o0 >> 9; }
    else        { tf2x32(K0, K1v, (uint32_t)(i - NH), (uint32_t)i, o0, o1); m = o1 >> 9; }
#endif
  }
  marr[i] = m;
  meta[i] = (mt & 0x3FF) | ((lab + 1) << 10);
}

// ---------------- selection: 3-level radix histogram over 42-bit keys ----------------
// key = (m << 19) | anchor_index  (distinct; matches stable argsort by (value, index))
__global__ void khist(const int* __restrict__ meta, const unsigned* __restrict__ marr,
                      const unsigned long long* __restrict__ prefix,
                      const int* __restrict__ Karr, int* __restrict__ hist,
                      int level, int N) {
  int stride = gridDim.x * blockDim.x;
  for (int i = blockIdx.x * blockDim.x + threadIdx.x; i < N; i += stride) {
    int lab = ((meta[i] >> 10) & 3) - 1;
    if (lab < 0) continue;
    int s = lab ? 0 : 1;                      // 0 = fg selection, 1 = bg selection
    if (level > 0 && Karr[s] <= 0) continue;
    unsigned long long key = ((unsigned long long)marr[i] << 19) | (unsigned)i;
    int bin;
    if (level == 0) bin = (int)(key >> 28);
    else if (level == 1) {
      if ((key >> 28) != prefix[s]) continue;
      bin = (int)((key >> 14) & 0x3FFF);
    } else {
      if ((key >> 14) != prefix[s]) continue;
      bin = (int)(key & 0x3FFF);
    }
    atomicAdd(&hist[s * 16384 + bin], 1);
  }
}

__global__ void kfind(int* hist, const int* counters, int* Karr,
                      unsigned long long* prefix, unsigned long long* thr,
                      int level) {
  __shared__ int part[256];
  __shared__ int s_selt, s_selk;
  int t = threadIdx.x;
  for (int s = 0; s < 2; ++s) {
    int K;
    if (level == 0) {
      int fgc = counters[0], bgc = counters[1];
      int fgk = min(fgc, 128);
      K = (s == 0) ? fgk : min(256 - fgk, bgc);
      if (t == 0) {
        Karr[s] = K;
        prefix[s] = 0ull;
        if (K <= 0) thr[s] = 0ull;   // keep nothing
      }
    } else {
      K = Karr[s];
    }
    __syncthreads();
    if (K > 0) {                       // K uniform across block
      const int base = s * 16384;
      int sum = 0;
      for (int b = 0; b < 64; ++b) sum += hist[base + t * 64 + b];
      part[t] = sum;
      __syncthreads();
      if (t == 0) {
        int cum = 0; s_selt = 0; s_selk = K;
        for (int q = 0; q < 256; ++q) {
          if (cum + part[q] >= K) { s_selt = q; s_selk = K - cum; break; }
          cum += part[q];
        }
      }
      __syncthreads();
      if (t == s_selt) {
        int cum = 0, Kc = s_selk;
        for (int b = 0; b < 64; ++b) {
          int h = hist[base + t * 64 + b];
          if (cum + h >= Kc) {
            Karr[s] = Kc - cum;        // remaining rank inside this bin
            unsigned long long p = (prefix[s] << 14) | (unsigned long long)(t * 64 + b);
            prefix[s] = p;
            if (level == 2) thr[s] = p + 1ull;   // keep iff key < thr
            break;
          }
          cum += h;
        }
      }
      __syncthreads();
    }
    for (int b = t; b < 16384; b += 256) hist[s * 16384 + b] = 0;  // ready for next level
    __syncthreads();
  }
}

// ---------------- K3: final labels / targets / weights ----------------
__global__ void k3_out(const float4* __restrict__ anch, const float* __restrict__ gt,
                       const int* __restrict__ meta, const unsigned* __restrict__ marr,
                       const int* __restrict__ counters,
                       const unsigned long long* __restrict__ thr,
                       float* __restrict__ out, int N) {
  int i = blockIdx.x * blockDim.x + threadIdx.x;
  if (i >= N) return;
  int mt = meta[i];
  int lab = ((mt >> 10) & 3) - 1;
  bool inside = (mt >> 9) & 1;
  int am = mt & 0x1FF;
  if (lab >= 0) {
    int s = lab ? 0 : 1;
    unsigned long long key = ((unsigned long long)marr[i] << 19) | (unsigned)i;
    if (key >= thr[s]) lab = -1;
  }
  int fgc = counters[0], bgc = counters[1];
  int fgk = min(fgc, 128);
  int ne = fgk + min(256 - fgk, bgc);   // num_examples after both subsamples
  out[i] = (float)lab;
  float4 tg = make_float4(0.0f, 0.0f, 0.0f, 0.0f);
  if (inside) {
    float4 a = anch[i];
    float g0 = gt[5*am], g1 = gt[5*am+1], g2 = gt[5*am+2], g3 = gt[5*am+3];
    float ew = __fadd_rn(__fsub_rn(a.z, a.x), 1.0f);
    float eh = __fadd_rn(__fsub_rn(a.w, a.y), 1.0f);
    float ecx = __fadd_rn(a.x, __fmul_rn(0.5f, ew));
    float ecy = __fadd_rn(a.y, __fmul_rn(0.5f, eh));
    float gw = __fadd_rn(__fsub_rn(g2, g0), 1.0f);
    float gh = __fadd_rn(__fsub_rn(g3, g1), 1.0f);
    float gcx = __fadd_rn(g0, __fmul_rn(0.5f, gw));
    float gcy = __fadd_rn(g1, __fmul_rn(0.5f, gh));
    tg = make_float4(__fdiv_rn(__fsub_rn(gcx, ecx), ew),
                     __fdiv_rn(__fsub_rn(gcy, ecy), eh),
                     logf(__fdiv_rn(gw, ew)),
                     logf(__fdiv_rn(gh, eh)));
  }
  reinterpret_cast<float4*>(out + (size_t)N)[i] = tg;
  float bw = (lab == 1) ? 1.0f : 0.0f;
  reinterpret_cast<float4*>(out + 5 * (size_t)N)[i] = make_float4(bw, bw, bw, bw);
  float ov = (lab >= 0) ? __fdiv_rn(1.0f, (float)ne) : 0.0f;
  reinterpret_cast<float4*>(out + 9 * (size_t)N)[i] = make_float4(ov, ov, ov, ov);
}

// ---------------- launch ----------------
extern "C" void kernel_launch(void* const* d_in, const int* in_sizes, int n_in,
                              void* d_out, int out_size, void* d_ws, size_t ws_size,
                              hipStream_t stream) {
  const float4* anch = (const float4*)d_in[3];
  const float* gt    = (const float*)d_in[1];
  const float* info  = (const float*)d_in[2];
  float* out = (float*)d_out;
  const int N = in_sizes[3] / 4;       // 331776  (< 2^19, required by key packing)
  const int G = in_sizes[1] / 5;       // 128

  char* ws = (char*)d_ws;
  int* gt_max                 = (int*)(ws + 0);        // 512 ints max
  int* counters               = (int*)(ws + 2048);     // fg, bg
  int* Karr                   = (int*)(ws + 2112);
  unsigned long long* prefix  = (unsigned long long*)(ws + 2176);
  unsigned long long* thr     = (unsigned long long*)(ws + 2240);
  int* hist                   = (int*)(ws + 4096);     // 2 * 16384 ints
  float* maxov                = (float*)(ws + 135168);
  int* meta                   = (int*)(ws + 135168 + 4 * (size_t)N);
  unsigned* marr              = (unsigned*)(ws + 135168 + 8 * (size_t)N);

  // host-side key derivation: kf, kb = split(key(42))
  uint32_t kf0, kf1, kb0, kb1;
#if RNG_PARTITIONABLE
  tf2x32(0u, 42u, 0u, 0u, kf0, kf1);
  tf2x32(0u, 42u, 0u, 1u, kb0, kb1);
#else
  {
    uint32_t a0, a1, b0, b1;
    tf2x32(0u, 42u, 0u, 2u, a0, a1);
    tf2x32(0u, 42u, 1u, 3u, b0, b1);
    kf0 = a0; kf1 = b0; kb0 = a1; kb1 = b1;
  }
#endif

  const int NB = (N + 255) / 256;
  k0_init<<<130, 256, 0, stream>>>(gt_max, counters, hist, G);
  k1_iou<<<NB, 256, 0, stream>>>(anch, gt, info, maxov, meta, gt_max, N, G);
  k2_label<<<NB, 256, 0, stream>>>(anch, gt, maxov, meta, gt_max, marr, counters,
                                   kf0, kf1, kb0, kb1, N, G);
  for (int lvl = 0; lvl < 3; ++lvl) {
    khist<<<256, 256, 0, stream>>>(meta, marr, prefix, Karr, hist, lvl, N);
    kfind<<<1, 256, 0, stream>>>(hist, counters, Karr, prefix, thr, lvl);
  }
  k3_out<<<NB, 256, 0, stream>>>(anch, gt, meta, marr, counters, thr, out, N);
}

// Round 4
// 147.551 us; speedup vs baseline: 19.5883x; 1.4816x over previous
//
#include <hip/hip_runtime.h>
#include <cstdint>

#define RNG_PARTITIONABLE 1

// ---------------- Threefry-2x32 (exact JAX schedule) ----------------
__host__ __device__ inline void tf2x32(uint32_t k0, uint32_t k1,
                                       uint32_t x0, uint32_t x1,
                                       uint32_t& o0, uint32_t& o1) {
  const uint32_t k2 = k0 ^ k1 ^ 0x1BD11BDAu;
#define ROT(v, r) (((v) << (r)) | ((v) >> (32 - (r))))
#define R4(a,b,c,d) \
  x0 += x1; x1 = ROT(x1, a); x1 ^= x0; \
  x0 += x1; x1 = ROT(x1, b); x1 ^= x0; \
  x0 += x1; x1 = ROT(x1, c); x1 ^= x0; \
  x0 += x1; x1 = ROT(x1, d); x1 ^= x0;
  x0 += k0; x1 += k1;
  R4(13,15,26,6)   x0 += k1; x1 += k2 + 1u;
  R4(17,29,16,24)  x0 += k2; x1 += k0 + 2u;
  R4(13,15,26,6)   x0 += k0; x1 += k1 + 3u;
  R4(17,29,16,24)  x0 += k1; x1 += k2 + 4u;
  R4(13,15,26,6)   x0 += k2; x1 += k0 + 5u;
  o0 = x0; o1 = x1;
#undef R4
#undef ROT
}

// ---------------- exact (contraction-free, IEEE) IoU ----------------
__device__ __forceinline__ float iou_fn(float ax0, float ay0, float ax1, float ay1,
                                        float g0, float g1, float g2, float g3,
                                        float area_a, float area_g) {
  float ix0 = fmaxf(ax0, g0);
  float iy0 = fmaxf(ay0, g1);
  float ix1 = fminf(ax1, g2);
  float iy1 = fminf(ay1, g3);
  float iw = fmaxf(__fsub_rn(ix1, ix0), 0.0f);
  float ih = fmaxf(__fsub_rn(iy1, iy0), 0.0f);
  float inter = __fmul_rn(iw, ih);
  float denom = __fadd_rn(__fsub_rn(__fadd_rn(area_a, area_g), inter), 1e-5f);
  return __fdiv_rn(inter, denom);
}

__device__ __forceinline__ float area_fn(float x0, float y0, float x1, float y1) {
  return __fmul_rn(fmaxf(__fsub_rn(x1, x0), 0.0f), fmaxf(__fsub_rn(y1, y0), 0.0f));
}

// ---------------- kgt: gt-major exact gt_max (no cross-lane reduction) --------
// Thread t owns gt j = t&127 (two threads per gt, each half of the anchor
// stream). Inside anchors are compacted to LDS per 256-anchor chunk; inner
// loop does broadcast LDS reads + register fmax. gt_max > 0 always holds for
// this data (every gt overlaps some inside anchor), so gmem init 0 is exact.
__global__ void __launch_bounds__(256) kgt(const float4* __restrict__ anch,
        const float* __restrict__ gt, const float* __restrict__ info,
        int* __restrict__ gmax, int N, int G) {
  __shared__ float4 sa4[256];
  __shared__ float sar[256];
  __shared__ float sred[256];
  __shared__ int wbase[4];
  __shared__ int scnt;
  const int t = threadIdx.x;
  const int j = t & 127;
  const int half = t >> 7;
  float g0 = 0.f, g1 = 0.f, g2 = 0.f, g3 = 0.f, ag = 0.f;
  if (j < G) {
    g0 = gt[5*j]; g1 = gt[5*j+1]; g2 = gt[5*j+2]; g3 = gt[5*j+3];
    ag = area_fn(g0, g1, g2, g3);
  }
  const float Himg = info[0], Wimg = info[1];
  float best = 0.0f;
  for (int base = blockIdx.x * 256; base < N; base += gridDim.x * 256) {
    int i = base + t;
    float4 a = make_float4(0.f, 0.f, 0.f, 0.f);
    bool val = false;
    if (i < N) {
      a = anch[i];
      val = (a.x >= 0.f) && (a.y >= 0.f) && (a.z < Wimg) && (a.w < Himg);
    }
    if (t == 0) scnt = 0;
    __syncthreads();
    unsigned long long b = __ballot(val);
    if ((t & 63) == 0) wbase[t >> 6] = atomicAdd(&scnt, __popcll(b));
    __syncthreads();
    if (val) {
      int slot = wbase[t >> 6] + __popcll(b & ((1ull << (t & 63)) - 1ull));
      sa4[slot] = a;
      sar[slot] = area_fn(a.x, a.y, a.z, a.w);
    }
    __syncthreads();
    int M = scnt;
    int mid = M >> 1;
    int klo = half ? mid : 0;
    int khi = half ? M : mid;
    if (j < G) {
      #pragma unroll 2
      for (int k = klo; k < khi; ++k) {
        float4 a4 = sa4[k];
        best = fmaxf(best, iou_fn(a4.x, a4.y, a4.z, a4.w, g0, g1, g2, g3, sar[k], ag));
      }
    }
    __syncthreads();   // protect sa4/scnt before next chunk
  }
  sred[t] = best;
  __syncthreads();
  if (t < 128) {
    float v = fmaxf(sred[t], sred[t + 128]);
    if (t < G) atomicMax(&gmax[t], __float_as_int(v));  // nonneg floats: int order == float order
  }
}

// ---------------- K1: fused anchor-major pass (2 anchors/thread) --------------
// per-anchor max/argmax + is_gt_best + label + counts + threefry + level-0 hist
__global__ void __launch_bounds__(256) K1(const float4* __restrict__ anch,
        const float* __restrict__ gt, const int* __restrict__ gmax,
        const float* __restrict__ info,
        int* __restrict__ meta, unsigned* __restrict__ marr,
        int* __restrict__ counters, int* __restrict__ hist,
        uint32_t kf0, uint32_t kf1, uint32_t kb0, uint32_t kb1,
        int N, int G) {
  __shared__ float4 sgt[128][2];   // {g0,g1,g2,g3} , {area, gt_max, 0, 0}
  __shared__ int cnt_s[2];
  const int t = threadIdx.x;
  if (t < 2) cnt_s[t] = 0;
  for (int q = t; q < G; q += 256) {
    float g0 = gt[5*q], g1 = gt[5*q+1], g2 = gt[5*q+2], g3 = gt[5*q+3];
    sgt[q][0] = make_float4(g0, g1, g2, g3);
    sgt[q][1] = make_float4(area_fn(g0, g1, g2, g3), __int_as_float(gmax[q]), 0.f, 0.f);
  }
  __syncthreads();
  const float Himg = info[0], Wimg = info[1];
  const int i0 = blockIdx.x * 512 + t;
  const int i1 = i0 + 256;
  float4 a0 = make_float4(0,0,0,0), a1 = make_float4(0,0,0,0);
  if (i0 < N) a0 = anch[i0];
  if (i1 < N) a1 = anch[i1];
  const bool in0 = (a0.x >= 0.0f) && (a0.y >= 0.0f) && (a0.z < Wimg) && (a0.w < Himg);
  const bool in1 = (a1.x >= 0.0f) && (a1.y >= 0.0f) && (a1.z < Wimg) && (a1.w < Himg);
  const float ar0 = area_fn(a0.x, a0.y, a0.z, a0.w);
  const float ar1 = area_fn(a1.x, a1.y, a1.z, a1.w);
  float b0 = -INFINITY, b1 = -INFINITY;
  int j0 = 0, j1 = 0;
  bool gb0 = false, gb1 = false;
  #pragma unroll 2
  for (int j = 0; j < G; ++j) {
    float4 p = sgt[j][0];
    float4 q = sgt[j][1];
    float iou0 = iou_fn(a0.x,a0.y,a0.z,a0.w, p.x,p.y,p.z,p.w, ar0, q.x);
    float iou1 = iou_fn(a1.x,a1.y,a1.z,a1.w, p.x,p.y,p.z,p.w, ar1, q.x);
    float m0 = in0 ? iou0 : -1.0f;
    float m1 = in1 ? iou1 : -1.0f;
    if (m0 > b0) { b0 = m0; j0 = j; }      // strict > keeps FIRST argmax
    if (m1 > b1) { b1 = m1; j1 = j; }
    gb0 = gb0 | (m0 == q.y);
    gb1 = gb1 | (m1 == q.y);
  }
  int lab0 = -1, lab1 = -1;
  if (in0) lab0 = (b0 < 0.3f) ? 0 : ((b0 >= 0.7f) ? 1 : (gb0 ? 1 : -1));
  if (in1) lab1 = (b1 < 0.3f) ? 0 : ((b1 >= 0.7f) ? 1 : (gb1 ? 1 : -1));
  // block-aggregated counts
  unsigned long long f0 = __ballot(lab0 == 1), z0 = __ballot(lab0 == 0);
  unsigned long long f1 = __ballot(lab1 == 1), z1 = __ballot(lab1 == 0);
  if ((t & 63) == 0) {
    int cf = __popcll(f0) + __popcll(f1);
    int cb = __popcll(z0) + __popcll(z1);
    if (cf) atomicAdd(&cnt_s[0], cf);
    if (cb) atomicAdd(&cnt_s[1], cb);
  }
  __syncthreads();
  if (t == 0) {
    if (cnt_s[0]) atomicAdd(&counters[0], cnt_s[0]);
    if (cnt_s[1]) atomicAdd(&counters[1], cnt_s[1]);
  }
  #pragma unroll
  for (int half = 0; half < 2; ++half) {
    int i = half ? i1 : i0;
    if (i >= N) continue;
    int lab = half ? lab1 : lab0;
    int bj  = half ? j1 : j0;
    bool ins = half ? in1 : in0;
    uint32_t K0 = (lab == 1) ? kf0 : kb0;
    uint32_t K1v = (lab == 1) ? kf1 : kb1;
    uint32_t o0, o1;
#if RNG_PARTITIONABLE
    tf2x32(K0, K1v, 0u, (uint32_t)i, o0, o1);
    unsigned m = (o0 ^ o1) >> 9;
#else
    unsigned m;
    int NH = N >> 1;
    if (i < NH) { tf2x32(K0, K1v, (uint32_t)i, (uint32_t)(i + NH), o0, o1); m = o0 >> 9; }
    else        { tf2x32(K0, K1v, (uint32_t)(i - NH), (uint32_t)i, o0, o1); m = o1 >> 9; }
#endif
    marr[i] = m;
    meta[i] = bj | (ins ? (1 << 9) : 0) | ((lab + 1) << 10);
    if (lab >= 0) {
      int s = lab ? 0 : 1;
      unsigned long long key = ((unsigned long long)m << 19) | (unsigned)i;
      atomicAdd(&hist[s * 16384 + (int)(key >> 28)], 1);
    }
  }
}

// ---------------- kresolveA: pick the K-th-containing bin + in-bin rank ------
__global__ void kresolveA(const int* __restrict__ counters, const int* __restrict__ hist,
                          int* __restrict__ binsel, unsigned long long* __restrict__ thr) {
  __shared__ int part[256];
  __shared__ int schunk;
  const int t = threadIdx.x;
  int fgc = counters[0], bgc = counters[1];
  int fgk = min(fgc, 128);
  int Ks[2] = { fgk, min(256 - fgk, bgc) };
  for (int s = 0; s < 2; ++s) {
    int K = Ks[s];
    if (K <= 0) {
      if (t == 0) { thr[s] = 0ull; binsel[s] = -1; }
      __syncthreads();
      continue;
    }
    const int* h = hist + s * 16384;
    int sum = 0;
    #pragma unroll
    for (int b = 0; b < 64; ++b) sum += h[t * 64 + b];
    part[t] = sum;
    __syncthreads();
    if (t == 0) {
      int cum = 0, rch = K;
      schunk = 255;
      for (int q = 0; q < 256; ++q) {
        if (cum + part[q] >= K) { schunk = q; rch = K - cum; break; }
        cum += part[q];
      }
      int cum2 = 0;
      for (int b = 0; b < 64; ++b) {
        int hv = h[schunk * 64 + b];
        if (cum2 + hv >= rch) {
          binsel[s] = schunk * 64 + b;     // selected bin
          binsel[2 + s] = rch - cum2;      // 1-indexed rank inside bin
          break;
        }
        cum2 += hv;
      }
    }
    __syncthreads();
  }
}

// ---------------- kcollect: gather keys of the selected bins -----------------
__global__ void kcollect(const int* __restrict__ meta, const unsigned* __restrict__ marr,
                         const int* __restrict__ binsel, int* __restrict__ colcnt,
                         unsigned long long* __restrict__ collected, int N) {
  const int b0 = binsel[0], b1 = binsel[1];
  int stride = gridDim.x * blockDim.x;
  for (int i = blockIdx.x * blockDim.x + threadIdx.x; i < N; i += stride) {
    int lab = ((meta[i] >> 10) & 3) - 1;
    if (lab < 0) continue;
    int s = lab ? 0 : 1;
    unsigned long long key = ((unsigned long long)marr[i] << 19) | (unsigned)i;
    if ((int)(key >> 28) != (s ? b1 : b0)) continue;
    int slot = atomicAdd(&colcnt[s], 1);
    if (slot < 1024) collected[s * 1024 + slot] = key;
  }
}

// ---------------- kresolveB: exact rank among collected keys -> threshold ----
__global__ void kresolveB(const int* __restrict__ counters, const int* __restrict__ binsel,
                          const int* __restrict__ colcnt,
                          const unsigned long long* __restrict__ collected,
                          unsigned long long* __restrict__ thr) {
  __shared__ unsigned long long keys[1024];
  const int t = threadIdx.x;
  int fgc = counters[0], bgc = counters[1];
  int fgk = min(fgc, 128);
  int Ks[2] = { fgk, min(256 - fgk, bgc) };
  for (int s = 0; s < 2; ++s) {
    __syncthreads();
    int K = Ks[s];
    if (K <= 0) continue;                  // thr written by kresolveA
    int n = min(colcnt[s], 1024);
    int r = binsel[2 + s];
    for (int kk = t; kk < n; kk += 256) keys[kk] = collected[s * 1024 + kk];
    __syncthreads();
    for (int kk = t; kk < n; kk += 256) {
      unsigned long long k = keys[kk];
      int rank = 0;
      for (int u = 0; u < n; ++u) rank += (keys[u] < k);
      if (rank == r - 1) thr[s] = k + 1ull; // keep iff key < thr
    }
  }
}

// ---------------- k3: final labels / targets / weights -----------------------
__global__ void k3_out(const float4* __restrict__ anch, const float* __restrict__ gt,
                       const int* __restrict__ meta, const unsigned* __restrict__ marr,
                       const int* __restrict__ counters,
                       const unsigned long long* __restrict__ thr,
                       float* __restrict__ out, int N) {
  int i = blockIdx.x * blockDim.x + threadIdx.x;
  if (i >= N) return;
  int mt = meta[i];
  int lab = ((mt >> 10) & 3) - 1;
  bool inside = (mt >> 9) & 1;
  int am = mt & 0x1FF;
  if (lab >= 0) {
    int s = lab ? 0 : 1;
    unsigned long long key = ((unsigned long long)marr[i] << 19) | (unsigned)i;
    if (key >= thr[s]) lab = -1;
  }
  int fgc = counters[0], bgc = counters[1];
  int fgk = min(fgc, 128);
  int ne = fgk + min(256 - fgk, bgc);
  out[i] = (float)lab;
  float4 tg = make_float4(0.0f, 0.0f, 0.0f, 0.0f);
  if (inside) {
    float4 a = anch[i];
    float g0 = gt[5*am], g1 = gt[5*am+1], g2 = gt[5*am+2], g3 = gt[5*am+3];
    float ew = __fadd_rn(__fsub_rn(a.z, a.x), 1.0f);
    float eh = __fadd_rn(__fsub_rn(a.w, a.y), 1.0f);
    float ecx = __fadd_rn(a.x, __fmul_rn(0.5f, ew));
    float ecy = __fadd_rn(a.y, __fmul_rn(0.5f, eh));
    float gw = __fadd_rn(__fsub_rn(g2, g0), 1.0f);
    float gh = __fadd_rn(__fsub_rn(g3, g1), 1.0f);
    float gcx = __fadd_rn(g0, __fmul_rn(0.5f, gw));
    float gcy = __fadd_rn(g1, __fmul_rn(0.5f, gh));
    tg = make_float4(__fdiv_rn(__fsub_rn(gcx, ecx), ew),
                     __fdiv_rn(__fsub_rn(gcy, ecy), eh),
                     logf(__fdiv_rn(gw, ew)),
                     logf(__fdiv_rn(gh, eh)));
  }
  reinterpret_cast<float4*>(out + (size_t)N)[i] = tg;
  float bw = (lab == 1) ? 1.0f : 0.0f;
  reinterpret_cast<float4*>(out + 5 * (size_t)N)[i] = make_float4(bw, bw, bw, bw);
  float ov = (lab >= 0) ? __fdiv_rn(1.0f, (float)ne) : 0.0f;
  reinterpret_cast<float4*>(out + 9 * (size_t)N)[i] = make_float4(ov, ov, ov, ov);
}

// ---------------- launch ----------------
extern "C" void kernel_launch(void* const* d_in, const int* in_sizes, int n_in,
                              void* d_out, int out_size, void* d_ws, size_t ws_size,
                              hipStream_t stream) {
  const float4* anch = (const float4*)d_in[3];
  const float* gt    = (const float*)d_in[1];
  const float* info  = (const float*)d_in[2];
  float* out = (float*)d_out;
  const int N = in_sizes[3] / 4;                 // 331776 (< 2^19 for key packing)
  const int G = in_sizes[1] / 5;                 // 128 (must be <= 128)

  // workspace layout (total ~2.80 MB)
  char* ws = (char*)d_ws;
  int* counters = (int*)(ws + 0);                //  2 ints
  int* colcnt   = (int*)(ws + 8);                //  2 ints
  int* binsel   = (int*)(ws + 16);               //  bin[2], r[2]
  int* gmax     = (int*)(ws + 64);               //  128 ints (float bits, init 0)
  int* hist     = (int*)(ws + 1024);             //  2*16384 ints -> end 132096
  unsigned long long* thr       = (unsigned long long*)(ws + 132096);
  unsigned long long* collected = (unsigned long long*)(ws + 132160); // 2*1024 u64
  unsigned* marr = (unsigned*)(ws + 148544);
  int* meta      = (int*)(ws + 148544 + 4ull * (size_t)N);

  // host-side key derivation: kf, kb = split(key(42))
  uint32_t kf0, kf1, kb0, kb1;
#if RNG_PARTITIONABLE
  tf2x32(0u, 42u, 0u, 0u, kf0, kf1);
  tf2x32(0u, 42u, 0u, 1u, kb0, kb1);
#else
  {
    uint32_t a0, a1, b0, b1;
    tf2x32(0u, 42u, 0u, 2u, a0, a1);
    tf2x32(0u, 42u, 1u, 3u, b0, b1);
    kf0 = a0; kf1 = b0; kb0 = a1; kb1 = b1;
  }
#endif

  hipMemsetAsync(ws, 0, 132096, stream);   // counters+colcnt+binsel+gmax+hist
  kgt<<<256, 256, 0, stream>>>(anch, gt, info, gmax, N, G);
  K1<<<(N + 511) / 512, 256, 0, stream>>>(anch, gt, gmax, info, meta, marr,
                                          counters, hist, kf0, kf1, kb0, kb1, N, G);
  kresolveA<<<1, 256, 0, stream>>>(counters, hist, binsel, thr);
  kcollect<<<128, 256, 0, stream>>>(meta, marr, binsel, colcnt, collected, N);
  kresolveB<<<1, 256, 0, stream>>>(counters, binsel, colcnt, collected, thr);
  k3_out<<<(N + 255) / 256, 256, 0, stream>>>(anch, gt, meta, marr, counters,
                                              thr, out, N);
}

// Round 5
// 120.867 us; speedup vs baseline: 23.9128x; 1.2208x over previous
//
#include <hip/hip_runtime.h>
#include <cstdint>

#define RNG_PARTITIONABLE 1

// ---------------- Threefry-2x32 (exact JAX schedule) ----------------
__host__ __device__ inline void tf2x32(uint32_t k0, uint32_t k1,
                                       uint32_t x0, uint32_t x1,
                                       uint32_t& o0, uint32_t& o1) {
  const uint32_t k2 = k0 ^ k1 ^ 0x1BD11BDAu;
#define ROT(v, r) (((v) << (r)) | ((v) >> (32 - (r))))
#define R4(a,b,c,d) \
  x0 += x1; x1 = ROT(x1, a); x1 ^= x0; \
  x0 += x1; x1 = ROT(x1, b); x1 ^= x0; \
  x0 += x1; x1 = ROT(x1, c); x1 ^= x0; \
  x0 += x1; x1 = ROT(x1, d); x1 ^= x0;
  x0 += k0; x1 += k1;
  R4(13,15,26,6)   x0 += k1; x1 += k2 + 1u;
  R4(17,29,16,24)  x0 += k2; x1 += k0 + 2u;
  R4(13,15,26,6)   x0 += k0; x1 += k1 + 3u;
  R4(17,29,16,24)  x0 += k1; x1 += k2 + 4u;
  R4(13,15,26,6)   x0 += k2; x1 += k0 + 5u;
  o0 = x0; o1 = x1;
#undef R4
#undef ROT
}

// ---------------- exact (contraction-free, IEEE) IoU ----------------
__device__ __forceinline__ float iou_fn(float ax0, float ay0, float ax1, float ay1,
                                        float g0, float g1, float g2, float g3,
                                        float area_a, float area_g) {
  float ix0 = fmaxf(ax0, g0);
  float iy0 = fmaxf(ay0, g1);
  float ix1 = fminf(ax1, g2);
  float iy1 = fminf(ay1, g3);
  float iw = fmaxf(__fsub_rn(ix1, ix0), 0.0f);
  float ih = fmaxf(__fsub_rn(iy1, iy0), 0.0f);
  float inter = __fmul_rn(iw, ih);
  float denom = __fadd_rn(__fsub_rn(__fadd_rn(area_a, area_g), inter), 1e-5f);
  return __fdiv_rn(inter, denom);
}

__device__ __forceinline__ float area_fn(float x0, float y0, float x1, float y1) {
  return __fmul_rn(fmaxf(__fsub_rn(x1, x0), 0.0f), fmaxf(__fsub_rn(y1, y0), 0.0f));
}

// ---------------- kgtA: per-chunk per-gt max -> slab (no atomics) ------------
// One block per 256-anchor chunk. Inside anchors compacted to LDS; thread t
// owns gt j = t&127 over half the chunk; 2-way LDS reduce; slab write.
__global__ void __launch_bounds__(256) kgtA(const float4* __restrict__ anch,
        const float* __restrict__ gt, const float* __restrict__ info,
        float* __restrict__ slab, int N, int G) {
  __shared__ float4 sa4[256];
  __shared__ float sar[256];
  __shared__ float sred[256];
  __shared__ int wbase[4];
  __shared__ int scnt;
  const int t = threadIdx.x;
  const int j = t & 127;
  const int half = t >> 7;
  float g0 = 0.f, g1 = 0.f, g2 = 0.f, g3 = 0.f, ag = 0.f;
  if (j < G) {
    g0 = gt[5*j]; g1 = gt[5*j+1]; g2 = gt[5*j+2]; g3 = gt[5*j+3];
    ag = area_fn(g0, g1, g2, g3);
  }
  const float Himg = info[0], Wimg = info[1];
  const int i = blockIdx.x * 256 + t;
  float4 a = make_float4(0.f, 0.f, 0.f, 0.f);
  bool val = false;
  if (i < N) {
    a = anch[i];
    val = (a.x >= 0.f) && (a.y >= 0.f) && (a.z < Wimg) && (a.w < Himg);
  }
  if (t == 0) scnt = 0;
  __syncthreads();
  unsigned long long b = __ballot(val);
  if ((t & 63) == 0) wbase[t >> 6] = atomicAdd(&scnt, __popcll(b));
  __syncthreads();
  if (val) {
    int slot = wbase[t >> 6] + __popcll(b & ((1ull << (t & 63)) - 1ull));
    sa4[slot] = a;
    sar[slot] = area_fn(a.x, a.y, a.z, a.w);
  }
  __syncthreads();
  const int M = scnt;
  const int mid = M >> 1;
  const int klo = half ? mid : 0;
  const int khi = half ? M : mid;
  float best = 0.0f;   // exact identity: every gt's true masked max is >= 0
  #pragma unroll 2
  for (int k = klo; k < khi; ++k) {
    float4 a4 = sa4[k];
    best = fmaxf(best, iou_fn(a4.x, a4.y, a4.z, a4.w, g0, g1, g2, g3, sar[k], ag));
  }
  sred[t] = best;
  __syncthreads();
  if (t < 128)
    slab[(size_t)blockIdx.x * 128 + t] = fmaxf(sred[t], sred[t + 128]);
}

// ---------------- kgtB: reduce slab column -> gmax (direct store) ------------
__global__ void __launch_bounds__(256) kgtB(const float* __restrict__ slab,
                                            int* __restrict__ gmax, int nchunks) {
  __shared__ float red[256];
  const int t = threadIdx.x;
  const int j = blockIdx.x;
  float best = 0.0f;
  for (int c = t; c < nchunks; c += 256)
    best = fmaxf(best, slab[(size_t)c * 128 + j]);
  red[t] = best;
  __syncthreads();
  #pragma unroll
  for (int s = 128; s > 0; s >>= 1) {
    if (t < s) red[t] = fmaxf(red[t], red[t + s]);
    __syncthreads();
  }
  if (t == 0) gmax[j] = __float_as_int(red[0]);
}

// ---------------- K1: fused anchor-major pass (2 anchors/thread) --------------
// per-anchor max/argmax + is_gt_best + label + counts + threefry + level-0 hist
__global__ void __launch_bounds__(256) K1(const float4* __restrict__ anch,
        const float* __restrict__ gt, const int* __restrict__ gmax,
        const float* __restrict__ info,
        int* __restrict__ meta, unsigned* __restrict__ marr,
        int* __restrict__ counters, int* __restrict__ hist,
        uint32_t kf0, uint32_t kf1, uint32_t kb0, uint32_t kb1,
        int N, int G) {
  __shared__ float4 sgt[128][2];   // {g0,g1,g2,g3} , {area, gt_max, 0, 0}
  __shared__ int cnt_s[2];
  const int t = threadIdx.x;
  if (t < 2) cnt_s[t] = 0;
  for (int q = t; q < G; q += 256) {
    float g0 = gt[5*q], g1 = gt[5*q+1], g2 = gt[5*q+2], g3 = gt[5*q+3];
    sgt[q][0] = make_float4(g0, g1, g2, g3);
    sgt[q][1] = make_float4(area_fn(g0, g1, g2, g3), __int_as_float(gmax[q]), 0.f, 0.f);
  }
  __syncthreads();
  const float Himg = info[0], Wimg = info[1];
  const int i0 = blockIdx.x * 512 + t;
  const int i1 = i0 + 256;
  float4 a0 = make_float4(0,0,0,0), a1 = make_float4(0,0,0,0);
  if (i0 < N) a0 = anch[i0];
  if (i1 < N) a1 = anch[i1];
  const bool in0 = (a0.x >= 0.0f) && (a0.y >= 0.0f) && (a0.z < Wimg) && (a0.w < Himg);
  const bool in1 = (a1.x >= 0.0f) && (a1.y >= 0.0f) && (a1.z < Wimg) && (a1.w < Himg);
  const float ar0 = area_fn(a0.x, a0.y, a0.z, a0.w);
  const float ar1 = area_fn(a1.x, a1.y, a1.z, a1.w);
  float b0 = -INFINITY, b1 = -INFINITY;
  int j0 = 0, j1 = 0;
  bool gb0 = false, gb1 = false;
  #pragma unroll 2
  for (int j = 0; j < G; ++j) {
    float4 p = sgt[j][0];
    float4 q = sgt[j][1];
    float iou0 = iou_fn(a0.x,a0.y,a0.z,a0.w, p.x,p.y,p.z,p.w, ar0, q.x);
    float iou1 = iou_fn(a1.x,a1.y,a1.z,a1.w, p.x,p.y,p.z,p.w, ar1, q.x);
    float m0 = in0 ? iou0 : -1.0f;
    float m1 = in1 ? iou1 : -1.0f;
    if (m0 > b0) { b0 = m0; j0 = j; }      // strict > keeps FIRST argmax
    if (m1 > b1) { b1 = m1; j1 = j; }
    gb0 = gb0 | (m0 == q.y);
    gb1 = gb1 | (m1 == q.y);
  }
  int lab0 = -1, lab1 = -1;
  if (in0) lab0 = (b0 < 0.3f) ? 0 : ((b0 >= 0.7f) ? 1 : (gb0 ? 1 : -1));
  if (in1) lab1 = (b1 < 0.3f) ? 0 : ((b1 >= 0.7f) ? 1 : (gb1 ? 1 : -1));
  // block-aggregated counts
  unsigned long long f0 = __ballot(lab0 == 1), z0 = __ballot(lab0 == 0);
  unsigned long long f1 = __ballot(lab1 == 1), z1 = __ballot(lab1 == 0);
  if ((t & 63) == 0) {
    int cf = __popcll(f0) + __popcll(f1);
    int cb = __popcll(z0) + __popcll(z1);
    if (cf) atomicAdd(&cnt_s[0], cf);
    if (cb) atomicAdd(&cnt_s[1], cb);
  }
  __syncthreads();
  if (t == 0) {
    if (cnt_s[0]) atomicAdd(&counters[0], cnt_s[0]);
    if (cnt_s[1]) atomicAdd(&counters[1], cnt_s[1]);
  }
  #pragma unroll
  for (int half = 0; half < 2; ++half) {
    int i = half ? i1 : i0;
    if (i >= N) continue;
    int lab = half ? lab1 : lab0;
    int bj  = half ? j1 : j0;
    bool ins = half ? in1 : in0;
    uint32_t K0 = (lab == 1) ? kf0 : kb0;
    uint32_t K1v = (lab == 1) ? kf1 : kb1;
    uint32_t o0, o1;
#if RNG_PARTITIONABLE
    tf2x32(K0, K1v, 0u, (uint32_t)i, o0, o1);
    unsigned m = (o0 ^ o1) >> 9;
#else
    unsigned m;
    int NH = N >> 1;
    if (i < NH) { tf2x32(K0, K1v, (uint32_t)i, (uint32_t)(i + NH), o0, o1); m = o0 >> 9; }
    else        { tf2x32(K0, K1v, (uint32_t)(i - NH), (uint32_t)i, o0, o1); m = o1 >> 9; }
#endif
    marr[i] = m;
    meta[i] = bj | (ins ? (1 << 9) : 0) | ((lab + 1) << 10);
    if (lab >= 0) {
      int s = lab ? 0 : 1;
      unsigned long long key = ((unsigned long long)m << 19) | (unsigned)i;
      atomicAdd(&hist[s * 16384 + (int)(key >> 28)], 1);
    }
  }
}

// ---------------- kresolveA: pick the K-th-containing bin + in-bin rank ------
__global__ void kresolveA(const int* __restrict__ counters, const int* __restrict__ hist,
                          int* __restrict__ binsel, unsigned long long* __restrict__ thr) {
  __shared__ int part[256];
  __shared__ int schunk;
  const int t = threadIdx.x;
  int fgc = counters[0], bgc = counters[1];
  int fgk = min(fgc, 128);
  int Ks[2] = { fgk, min(256 - fgk, bgc) };
  for (int s = 0; s < 2; ++s) {
    int K = Ks[s];
    if (K <= 0) {
      if (t == 0) { thr[s] = 0ull; binsel[s] = -1; }
      __syncthreads();
      continue;
    }
    const int* h = hist + s * 16384;
    int sum = 0;
    #pragma unroll
    for (int b = 0; b < 64; ++b) sum += h[t * 64 + b];
    part[t] = sum;
    __syncthreads();
    if (t == 0) {
      int cum = 0, rch = K;
      schunk = 255;
      for (int q = 0; q < 256; ++q) {
        if (cum + part[q] >= K) { schunk = q; rch = K - cum; break; }
        cum += part[q];
      }
      int cum2 = 0;
      for (int b = 0; b < 64; ++b) {
        int hv = h[schunk * 64 + b];
        if (cum2 + hv >= rch) {
          binsel[s] = schunk * 64 + b;     // selected bin
          binsel[2 + s] = rch - cum2;      // 1-indexed rank inside bin
          break;
        }
        cum2 += hv;
      }
    }
    __syncthreads();
  }
}

// ---------------- kcollect: gather keys of the selected bins -----------------
__global__ void kcollect(const int* __restrict__ meta, const unsigned* __restrict__ marr,
                         const int* __restrict__ binsel, int* __restrict__ colcnt,
                         unsigned long long* __restrict__ collected, int N) {
  const int b0 = binsel[0], b1 = binsel[1];
  int stride = gridDim.x * blockDim.x;
  for (int i = blockIdx.x * blockDim.x + threadIdx.x; i < N; i += stride) {
    int lab = ((meta[i] >> 10) & 3) - 1;
    if (lab < 0) continue;
    int s = lab ? 0 : 1;
    unsigned long long key = ((unsigned long long)marr[i] << 19) | (unsigned)i;
    if ((int)(key >> 28) != (s ? b1 : b0)) continue;
    int slot = atomicAdd(&colcnt[s], 1);
    if (slot < 1024) collected[s * 1024 + slot] = key;
  }
}

// ---------------- kresolveB: exact rank among collected keys -> threshold ----
__global__ void kresolveB(const int* __restrict__ counters, const int* __restrict__ binsel,
                          const int* __restrict__ colcnt,
                          const unsigned long long* __restrict__ collected,
                          unsigned long long* __restrict__ thr) {
  __shared__ unsigned long long keys[1024];
  const int t = threadIdx.x;
  int fgc = counters[0], bgc = counters[1];
  int fgk = min(fgc, 128);
  int Ks[2] = { fgk, min(256 - fgk, bgc) };
  for (int s = 0; s < 2; ++s) {
    __syncthreads();
    int K = Ks[s];
    if (K <= 0) continue;                  // thr written by kresolveA
    int n = min(colcnt[s], 1024);
    int r = binsel[2 + s];
    for (int kk = t; kk < n; kk += 256) keys[kk] = collected[s * 1024 + kk];
    __syncthreads();
    for (int kk = t; kk < n; kk += 256) {
      unsigned long long k = keys[kk];
      int rank = 0;
      for (int u = 0; u < n; ++u) rank += (keys[u] < k);
      if (rank == r - 1) thr[s] = k + 1ull; // keep iff key < thr
    }
  }
}

// ---------------- k3: final labels / targets / weights -----------------------
__global__ void k3_out(const float4* __restrict__ anch, const float* __restrict__ gt,
                       const int* __restrict__ meta, const unsigned* __restrict__ marr,
                       const int* __restrict__ counters,
                       const unsigned long long* __restrict__ thr,
                       float* __restrict__ out, int N) {
  int i = blockIdx.x * blockDim.x + threadIdx.x;
  if (i >= N) return;
  int mt = meta[i];
  int lab = ((mt >> 10) & 3) - 1;
  bool inside = (mt >> 9) & 1;
  int am = mt & 0x1FF;
  if (lab >= 0) {
    int s = lab ? 0 : 1;
    unsigned long long key = ((unsigned long long)marr[i] << 19) | (unsigned)i;
    if (key >= thr[s]) lab = -1;
  }
  int fgc = counters[0], bgc = counters[1];
  int fgk = min(fgc, 128);
  int ne = fgk + min(256 - fgk, bgc);
  out[i] = (float)lab;
  float4 tg = make_float4(0.0f, 0.0f, 0.0f, 0.0f);
  if (inside) {
    float4 a = anch[i];
    float g0 = gt[5*am], g1 = gt[5*am+1], g2 = gt[5*am+2], g3 = gt[5*am+3];
    float ew = __fadd_rn(__fsub_rn(a.z, a.x), 1.0f);
    float eh = __fadd_rn(__fsub_rn(a.w, a.y), 1.0f);
    float ecx = __fadd_rn(a.x, __fmul_rn(0.5f, ew));
    float ecy = __fadd_rn(a.y, __fmul_rn(0.5f, eh));
    float gw = __fadd_rn(__fsub_rn(g2, g0), 1.0f);
    float gh = __fadd_rn(__fsub_rn(g3, g1), 1.0f);
    float gcx = __fadd_rn(g0, __fmul_rn(0.5f, gw));
    float gcy = __fadd_rn(g1, __fmul_rn(0.5f, gh));
    tg = make_float4(__fdiv_rn(__fsub_rn(gcx, ecx), ew),
                     __fdiv_rn(__fsub_rn(gcy, ecy), eh),
                     logf(__fdiv_rn(gw, ew)),
                     logf(__fdiv_rn(gh, eh)));
  }
  reinterpret_cast<float4*>(out + (size_t)N)[i] = tg;
  float bw = (lab == 1) ? 1.0f : 0.0f;
  reinterpret_cast<float4*>(out + 5 * (size_t)N)[i] = make_float4(bw, bw, bw, bw);
  float ov = (lab >= 0) ? __fdiv_rn(1.0f, (float)ne) : 0.0f;
  reinterpret_cast<float4*>(out + 9 * (size_t)N)[i] = make_float4(ov, ov, ov, ov);
}

// ---------------- launch ----------------
extern "C" void kernel_launch(void* const* d_in, const int* in_sizes, int n_in,
                              void* d_out, int out_size, void* d_ws, size_t ws_size,
                              hipStream_t stream) {
  const float4* anch = (const float4*)d_in[3];
  const float* gt    = (const float*)d_in[1];
  const float* info  = (const float*)d_in[2];
  float* out = (float*)d_out;
  const int N = in_sizes[3] / 4;                 // 331776 (< 2^19 for key packing)
  const int G = in_sizes[1] / 5;                 // 128 (must be <= 128)
  const int NCH = (N + 255) / 256;               // 1296 chunks

  // workspace layout (~3.47 MB; rounds 1-2 proved >= 4.1 MB available)
  char* ws = (char*)d_ws;
  int* counters = (int*)(ws + 0);                //  2 ints
  int* colcnt   = (int*)(ws + 8);                //  2 ints
  int* binsel   = (int*)(ws + 16);               //  bin[2], r[2]
  int* gmax     = (int*)(ws + 64);               //  128 ints (float bits)
  int* hist     = (int*)(ws + 1024);             //  2*16384 ints -> end 132096
  unsigned long long* thr       = (unsigned long long*)(ws + 132096);
  unsigned long long* collected = (unsigned long long*)(ws + 132160); // 2*1024 u64
  float* slab    = (float*)(ws + 148544);        //  NCH*128 floats
  size_t slab_end = 148544 + (size_t)NCH * 128 * 4;
  unsigned* marr = (unsigned*)(ws + slab_end);
  int* meta      = (int*)(ws + slab_end + 4ull * (size_t)N);

  // host-side key derivation: kf, kb = split(key(42))
  uint32_t kf0, kf1, kb0, kb1;
#if RNG_PARTITIONABLE
  tf2x32(0u, 42u, 0u, 0u, kf0, kf1);
  tf2x32(0u, 42u, 0u, 1u, kb0, kb1);
#else
  {
    uint32_t a0, a1, b0, b1;
    tf2x32(0u, 42u, 0u, 2u, a0, a1);
    tf2x32(0u, 42u, 1u, 3u, b0, b1);
    kf0 = a0; kf1 = b0; kb0 = a1; kb1 = b1;
  }
#endif

  hipMemsetAsync(ws, 0, 132096, stream);   // counters+colcnt+binsel+gmax+hist
  kgtA<<<NCH, 256, 0, stream>>>(anch, gt, info, slab, N, G);
  kgtB<<<G, 256, 0, stream>>>(slab, gmax, NCH);
  K1<<<(N + 511) / 512, 256, 0, stream>>>(anch, gt, gmax, info, meta, marr,
                                          counters, hist, kf0, kf1, kb0, kb1, N, G);
  kresolveA<<<1, 256, 0, stream>>>(counters, hist, binsel, thr);
  kcollect<<<128, 256, 0, stream>>>(meta, marr, binsel, colcnt, collected, N);
  kresolveB<<<1, 256, 0, stream>>>(counters, binsel, colcnt, collected, thr);
  k3_out<<<(N + 255) / 256, 256, 0, stream>>>(anch, gt, meta, marr, counters,
                                              thr, out, N);
}

// Round 6
// 104.422 us; speedup vs baseline: 27.6787x; 1.1575x over previous
//
#include <hip/hip_runtime.h>
#include <cstdint>

#define RNG_PARTITIONABLE 1

// ---------------- Threefry-2x32 (exact JAX schedule) ----------------
__host__ __device__ inline void tf2x32(uint32_t k0, uint32_t k1,
                                       uint32_t x0, uint32_t x1,
                                       uint32_t& o0, uint32_t& o1) {
  const uint32_t k2 = k0 ^ k1 ^ 0x1BD11BDAu;
#define ROT(v, r) (((v) << (r)) | ((v) >> (32 - (r))))
#define R4(a,b,c,d) \
  x0 += x1; x1 = ROT(x1, a); x1 ^= x0; \
  x0 += x1; x1 = ROT(x1, b); x1 ^= x0; \
  x0 += x1; x1 = ROT(x1, c); x1 ^= x0; \
  x0 += x1; x1 = ROT(x1, d); x1 ^= x0;
  x0 += k0; x1 += k1;
  R4(13,15,26,6)   x0 += k1; x1 += k2 + 1u;
  R4(17,29,16,24)  x0 += k2; x1 += k0 + 2u;
  R4(13,15,26,6)   x0 += k0; x1 += k1 + 3u;
  R4(17,29,16,24)  x0 += k1; x1 += k2 + 4u;
  R4(13,15,26,6)   x0 += k2; x1 += k0 + 5u;
  o0 = x0; o1 = x1;
#undef R4
#undef ROT
}

// ---------------- exact (contraction-free, IEEE) IoU ----------------
__device__ __forceinline__ float iou_fn(float ax0, float ay0, float ax1, float ay1,
                                        float g0, float g1, float g2, float g3,
                                        float area_a, float area_g) {
  float ix0 = fmaxf(ax0, g0);
  float iy0 = fmaxf(ay0, g1);
  float ix1 = fminf(ax1, g2);
  float iy1 = fminf(ay1, g3);
  float iw = fmaxf(__fsub_rn(ix1, ix0), 0.0f);
  float ih = fmaxf(__fsub_rn(iy1, iy0), 0.0f);
  float inter = __fmul_rn(iw, ih);
  float denom = __fadd_rn(__fsub_rn(__fadd_rn(area_a, area_g), inter), 1e-5f);
  return __fdiv_rn(inter, denom);
}

__device__ __forceinline__ float area_fn(float x0, float y0, float x1, float y1) {
  return __fmul_rn(fmaxf(__fsub_rn(x1, x0), 0.0f), fmaxf(__fsub_rn(y1, y0), 0.0f));
}

// ---------------- K1a: anchor-major; wave-bbox skip; fused per-gt slab -------
// Per anchor: max/argmax class (lo/mid/hi) + meta0. Per gt: block partial max
// via shfl-reduce only on overlapping (full-path) j's -> slab (no atomic storm).
// Non-overlapping pairs have iou == +0 exactly (skip is bit-exact).
__global__ void __launch_bounds__(256) K1a(const float4* __restrict__ anch,
        const float* __restrict__ gt, const float* __restrict__ info,
        int* __restrict__ meta, float* __restrict__ slab, int N, int G) {
  __shared__ float4 sg[128];
  __shared__ float sga[128];
  __shared__ int smax[128];
  const int t = threadIdx.x;
  for (int q = t; q < G; q += 256) {
    float g0 = gt[5*q], g1 = gt[5*q+1], g2 = gt[5*q+2], g3 = gt[5*q+3];
    sg[q] = make_float4(g0, g1, g2, g3);
    sga[q] = area_fn(g0, g1, g2, g3);
    smax[q] = 0;                       // 0.0f bits (valid: true gt-max >= 0)
  }
  __syncthreads();
  const float Himg = info[0], Wimg = info[1];
  const int i = blockIdx.x * 256 + t;
  float4 a = make_float4(0.f, 0.f, 0.f, 0.f);
  bool inside = false;
  float area_a = 0.f;
  float ex0 = INFINITY, ey0 = INFINITY, ex1 = -INFINITY, ey1 = -INFINITY;
  if (i < N) {
    a = anch[i];
    inside = (a.x >= 0.f) && (a.y >= 0.f) && (a.z < Wimg) && (a.w < Himg);
    if (inside) { ex0 = a.x; ey0 = a.y; ex1 = a.z; ey1 = a.w; }
    area_a = area_fn(a.x, a.y, a.z, a.w);
  }
  // wave bbox over inside lanes (conservative superset test)
  float wx0 = ex0, wy0 = ey0, wx1 = ex1, wy1 = ey1;
  #pragma unroll
  for (int d = 32; d; d >>= 1) {
    wx0 = fminf(wx0, __shfl_xor(wx0, d));
    wy0 = fminf(wy0, __shfl_xor(wy0, d));
    wx1 = fmaxf(wx1, __shfl_xor(wx1, d));
    wy1 = fmaxf(wy1, __shfl_xor(wy1, d));
  }
  float best = inside ? 0.0f : -1.0f;  // all-zero/-1 rows: argmax = 0 (matches ref)
  int bj = 0;
  const int lane0 = ((t & 63) == 0);
  for (int j = 0; j < G; ++j) {
    // uniform-address loads (scalarizable) for the wave-level reject
    const float g0 = gt[5*j], g1 = gt[5*j+1], g2 = gt[5*j+2], g3 = gt[5*j+3];
    if (wx0 < g2 && g0 < wx1 && wy0 < g3 && g1 < wy1) {   // uniform branch
      float4 p = sg[j];
      float iou = iou_fn(a.x, a.y, a.z, a.w, p.x, p.y, p.z, p.w, area_a, sga[j]);
      float mval = inside ? iou : -1.0f;
      if (mval > best) { best = mval; bj = j; }           // strict >: FIRST argmax
      float w = mval;                                     // exact fmax reduce
      #pragma unroll
      for (int d = 32; d; d >>= 1) w = fmaxf(w, __shfl_xor(w, d));
      if (lane0) atomicMax(&smax[j], __float_as_int(w));  // w<0 int-neg < 0 init
    }
  }
  if (i < N) {
    int cls = (best < 0.3f) ? 0 : ((best >= 0.7f) ? 2 : 1);
    meta[i] = bj | (inside ? 512 : 0) | (cls << 10);
  }
  __syncthreads();
  for (int q = t; q < G; q += 256)
    slab[(size_t)blockIdx.x * 128 + q] = __int_as_float(smax[q]);
}

// ---------------- kgtB: reduce slab column -> gmax ---------------------------
__global__ void __launch_bounds__(256) kgtB(const float* __restrict__ slab,
                                            int* __restrict__ gmax, int nchunks) {
  __shared__ float red[256];
  const int t = threadIdx.x;
  const int j = blockIdx.x;
  float best = 0.0f;
  for (int c = t; c < nchunks; c += 256)
    best = fmaxf(best, slab[(size_t)c * 128 + j]);
  red[t] = best;
  __syncthreads();
  #pragma unroll
  for (int s = 128; s > 0; s >>= 1) {
    if (t < s) red[t] = fmaxf(red[t], red[t + s]);
    __syncthreads();
  }
  if (t == 0) gmax[j] = __float_as_int(red[0]);
}

// ---------------- K1c: labels (is_gt_best only for mid class) + rng + hist ---
__global__ void __launch_bounds__(256) K1c(const float4* __restrict__ anch,
        const float* __restrict__ gt, const int* __restrict__ gmax,
        int* __restrict__ meta, unsigned* __restrict__ marr,
        int* __restrict__ counters, int* __restrict__ hist,
        uint32_t kf0, uint32_t kf1, uint32_t kb0, uint32_t kb1,
        int N, int G) {
  __shared__ float4 sg[128];
  __shared__ float sga[128];
  __shared__ float sgm[128];
  __shared__ int cnt_s[2];
  __shared__ int zlist[16];
  __shared__ int zn;
  const int t = threadIdx.x;
  if (t == 0) zn = 0;
  if (t < 2) cnt_s[t] = 0;
  for (int q = t; q < G; q += 256) {
    float g0 = gt[5*q], g1 = gt[5*q+1], g2 = gt[5*q+2], g3 = gt[5*q+3];
    sg[q] = make_float4(g0, g1, g2, g3);
    sga[q] = area_fn(g0, g1, g2, g3);
    float gm = __int_as_float(gmax[q]);
    sgm[q] = gm;
    if (gm == 0.0f) { int p = atomicAdd(&zn, 1); if (p < 16) zlist[p] = q; }
  }
  __syncthreads();
  const int i = blockIdx.x * 256 + t;
  int mt = 0; bool inside = false; int cls = 0;
  float4 a = make_float4(0.f, 0.f, 0.f, 0.f);
  if (i < N) {
    mt = meta[i];
    inside = (mt >> 9) & 1;
    cls = (mt >> 10) & 3;
  }
  const bool need = (i < N) && inside && (cls == 1);
  bool gbest = false;
  if (__any(need)) {
    float area_a = 0.f;
    if (i < N) { a = anch[i]; area_a = area_fn(a.x, a.y, a.z, a.w); }
    float ex0 = need ? a.x : INFINITY,  ey0 = need ? a.y : INFINITY;
    float ex1 = need ? a.z : -INFINITY, ey1 = need ? a.w : -INFINITY;
    float wx0 = ex0, wy0 = ey0, wx1 = ex1, wy1 = ey1;
    #pragma unroll
    for (int d = 32; d; d >>= 1) {
      wx0 = fminf(wx0, __shfl_xor(wx0, d));
      wy0 = fminf(wy0, __shfl_xor(wy0, d));
      wx1 = fmaxf(wx1, __shfl_xor(wx1, d));
      wy1 = fmaxf(wy1, __shfl_xor(wy1, d));
    }
    for (int j = 0; j < G; ++j) {
      const float g0 = gt[5*j], g1 = gt[5*j+1], g2 = gt[5*j+2], g3 = gt[5*j+3];
      if (wx0 < g2 && g0 < wx1 && wy0 < g3 && g1 < wy1) {
        float4 p = sg[j];
        float iou = iou_fn(a.x, a.y, a.z, a.w, p.x, p.y, p.z, p.w, area_a, sga[j]);
        gbest = gbest | (need && (iou == sgm[j]));
      }
    }
    // exact handling of degenerate gmax==0 gts: iou==0==gmax  <=>  no overlap
    for (int z = 0; z < 16; ++z) {
      if (z >= zn) break;
      float4 p = sg[zlist[z]];
      bool ov = (a.x < p.z) && (p.x < a.z) && (a.y < p.w) && (p.y < a.w);
      gbest = gbest | (need && !ov);
    }
  }
  int lab = -1;
  if (i < N && inside)
    lab = (cls == 0) ? 0 : ((cls == 2) ? 1 : (gbest ? 1 : -1));
  unsigned long long bf = __ballot(lab == 1), bb = __ballot(lab == 0);
  if ((t & 63) == 0) {
    if (bf) atomicAdd(&cnt_s[0], __popcll(bf));
    if (bb) atomicAdd(&cnt_s[1], __popcll(bb));
  }
  __syncthreads();
  if (t == 0) {
    if (cnt_s[0]) atomicAdd(&counters[0], cnt_s[0]);
    if (cnt_s[1]) atomicAdd(&counters[1], cnt_s[1]);
  }
  if (i >= N) return;
  uint32_t Kk0 = (lab == 1) ? kf0 : kb0;
  uint32_t Kk1 = (lab == 1) ? kf1 : kb1;
  uint32_t o0, o1;
#if RNG_PARTITIONABLE
  tf2x32(Kk0, Kk1, 0u, (uint32_t)i, o0, o1);
  unsigned m = (o0 ^ o1) >> 9;
#else
  unsigned m;
  int NH = N >> 1;
  if (i < NH) { tf2x32(Kk0, Kk1, (uint32_t)i, (uint32_t)(i + NH), o0, o1); m = o0 >> 9; }
  else        { tf2x32(Kk0, Kk1, (uint32_t)(i - NH), (uint32_t)i, o0, o1); m = o1 >> 9; }
#endif
  marr[i] = m;
  meta[i] = (mt & 0xFFF) | ((lab + 1) << 12);
  if (lab >= 0) {
    int s = lab ? 0 : 1;
    unsigned long long key = ((unsigned long long)m << 19) | (unsigned)i;
    atomicAdd(&hist[s * 16384 + (int)(key >> 28)], 1);
  }
}

// ---------------- kcollect (+resolveA prologue per block) --------------------
__global__ void __launch_bounds__(256) kcollect(const int* __restrict__ counters,
        const int* __restrict__ hist, const int* __restrict__ meta,
        const unsigned* __restrict__ marr, int* __restrict__ binsel_g,
        int* __restrict__ colcnt, unsigned long long* __restrict__ collected, int N) {
  __shared__ int part[256];
  __shared__ int sbin[2], srank[2];
  __shared__ int schunk;
  const int t = threadIdx.x;
  int fgc = counters[0], bgc = counters[1];
  int fgk = min(fgc, 128);
  int Ks[2] = { fgk, min(256 - fgk, bgc) };
  for (int s = 0; s < 2; ++s) {
    int K = Ks[s];
    if (K <= 0) {                        // uniform branch
      if (t == 0) { sbin[s] = -1; srank[s] = 0; }
      __syncthreads();
      continue;
    }
    const int* h = hist + s * 16384;
    int sum = 0;
    #pragma unroll
    for (int b = 0; b < 64; ++b) sum += h[t * 64 + b];
    part[t] = sum;
    __syncthreads();
    if (t == 0) {
      int cum = 0, rch = K; schunk = 255;
      for (int q = 0; q < 256; ++q) {
        if (cum + part[q] >= K) { schunk = q; rch = K - cum; break; }
        cum += part[q];
      }
      int cum2 = 0;
      for (int b = 0; b < 64; ++b) {
        int hv = h[schunk * 64 + b];
        if (cum2 + hv >= rch) { sbin[s] = schunk * 64 + b; srank[s] = rch - cum2; break; }
        cum2 += hv;
      }
    }
    __syncthreads();
  }
  if (blockIdx.x == 0 && t < 2) { binsel_g[t] = sbin[t]; binsel_g[2 + t] = srank[t]; }
  const int b0 = sbin[0], b1 = sbin[1];
  int stride = gridDim.x * blockDim.x;
  for (int i = blockIdx.x * blockDim.x + t; i < N; i += stride) {
    int lab = ((meta[i] >> 12) & 3) - 1;
    if (lab < 0) continue;
    int s = lab ? 0 : 1;
    unsigned long long key = ((unsigned long long)marr[i] << 19) | (unsigned)i;
    if ((int)(key >> 28) != (s ? b1 : b0)) continue;
    int slot = atomicAdd(&colcnt[s], 1);
    if (slot < 1024) collected[s * 1024 + slot] = key;
  }
}

// ---------------- k3 (+resolveB prologue): final outputs ---------------------
__global__ void __launch_bounds__(256) k3_out(const float4* __restrict__ anch,
        const float* __restrict__ gt, const int* __restrict__ meta,
        const unsigned* __restrict__ marr, const int* __restrict__ counters,
        const int* __restrict__ binsel_g, const int* __restrict__ colcnt,
        const unsigned long long* __restrict__ collected,
        float* __restrict__ out, int N) {
  __shared__ unsigned long long skeys[1024];
  __shared__ unsigned long long sthr[2];
  const int t = threadIdx.x;
  int fgc = counters[0], bgc = counters[1];
  int fgk = min(fgc, 128);
  int Ks[2] = { fgk, min(256 - fgk, bgc) };
  for (int s = 0; s < 2; ++s) {
    if (Ks[s] <= 0) {                    // uniform
      if (t == 0) sthr[s] = 0ull;
      __syncthreads(); __syncthreads();
      continue;
    }
    int n = min(colcnt[s], 1024);
    int r = binsel_g[2 + s];
    for (int kk = t; kk < n; kk += 256) skeys[kk] = collected[s * 1024 + kk];
    __syncthreads();
    for (int kk = t; kk < n; kk += 256) {
      unsigned long long k = skeys[kk];
      int rank = 0;
      for (int u = 0; u < n; ++u) rank += (skeys[u] < k);
      if (rank == r - 1) sthr[s] = k + 1ull;  // keep iff key < thr
    }
    __syncthreads();
  }
  const int ne = fgk + min(256 - fgk, bgc);
  int i = blockIdx.x * blockDim.x + t;
  if (i >= N) return;
  int mt = meta[i];
  int lab = ((mt >> 12) & 3) - 1;
  bool inside = (mt >> 9) & 1;
  int am = mt & 0x1FF;
  if (lab >= 0) {
    int s = lab ? 0 : 1;
    unsigned long long key = ((unsigned long long)marr[i] << 19) | (unsigned)i;
    if (key >= sthr[s]) lab = -1;
  }
  out[i] = (float)lab;
  float4 tg = make_float4(0.0f, 0.0f, 0.0f, 0.0f);
  if (inside) {
    float4 a = anch[i];
    float g0 = gt[5*am], g1 = gt[5*am+1], g2 = gt[5*am+2], g3 = gt[5*am+3];
    float ew = __fadd_rn(__fsub_rn(a.z, a.x), 1.0f);
    float eh = __fadd_rn(__fsub_rn(a.w, a.y), 1.0f);
    float ecx = __fadd_rn(a.x, __fmul_rn(0.5f, ew));
    float ecy = __fadd_rn(a.y, __fmul_rn(0.5f, eh));
    float gw = __fadd_rn(__fsub_rn(g2, g0), 1.0f);
    float gh = __fadd_rn(__fsub_rn(g3, g1), 1.0f);
    float gcx = __fadd_rn(g0, __fmul_rn(0.5f, gw));
    float gcy = __fadd_rn(g1, __fmul_rn(0.5f, gh));
    tg = make_float4(__fdiv_rn(__fsub_rn(gcx, ecx), ew),
                     __fdiv_rn(__fsub_rn(gcy, ecy), eh),
                     logf(__fdiv_rn(gw, ew)),
                     logf(__fdiv_rn(gh, eh)));
  }
  reinterpret_cast<float4*>(out + (size_t)N)[i] = tg;
  float bw = (lab == 1) ? 1.0f : 0.0f;
  reinterpret_cast<float4*>(out + 5 * (size_t)N)[i] = make_float4(bw, bw, bw, bw);
  float ov = (lab >= 0) ? __fdiv_rn(1.0f, (float)ne) : 0.0f;
  reinterpret_cast<float4*>(out + 9 * (size_t)N)[i] = make_float4(ov, ov, ov, ov);
}

// ---------------- launch ----------------
extern "C" void kernel_launch(void* const* d_in, const int* in_sizes, int n_in,
                              void* d_out, int out_size, void* d_ws, size_t ws_size,
                              hipStream_t stream) {
  const float4* anch = (const float4*)d_in[3];
  const float* gt    = (const float*)d_in[1];
  const float* info  = (const float*)d_in[2];
  float* out = (float*)d_out;
  const int N = in_sizes[3] / 4;                 // 331776 (< 2^19 for key packing)
  const int G = in_sizes[1] / 5;                 // 128 (must be <= 128)
  const int NCH = (N + 255) / 256;               // 1296 chunks

  // workspace layout (~3.31 MB)
  char* ws = (char*)d_ws;
  int* counters = (int*)(ws + 0);                // 2 ints
  int* colcnt   = (int*)(ws + 8);                // 2 ints
  int* binsel   = (int*)(ws + 16);               // bin[2], rank[2]
  int* gmax     = (int*)(ws + 64);               // 128 ints (float bits)
  int* hist     = (int*)(ws + 1024);             // 2*16384 ints -> end 132096
  unsigned long long* collected = (unsigned long long*)(ws + 132096); // 2*1024 u64 -> 148480
  float* slab    = (float*)(ws + 148480);        // NCH*128 floats -> 812032
  size_t slab_end = 148480 + (size_t)NCH * 128 * 4;
  unsigned* marr = (unsigned*)(ws + slab_end);
  int* meta      = (int*)(ws + slab_end + 4ull * (size_t)N);

  // host-side key derivation: kf, kb = split(key(42))
  uint32_t kf0, kf1, kb0, kb1;
#if RNG_PARTITIONABLE
  tf2x32(0u, 42u, 0u, 0u, kf0, kf1);
  tf2x32(0u, 42u, 0u, 1u, kb0, kb1);
#else
  {
    uint32_t a0, a1, b0, b1;
    tf2x32(0u, 42u, 0u, 2u, a0, a1);
    tf2x32(0u, 42u, 1u, 3u, b0, b1);
    kf0 = a0; kf1 = b0; kb0 = a1; kb1 = b1;
  }
#endif

  hipMemsetAsync(ws, 0, 132096, stream);   // counters+colcnt+binsel+gmax+hist
  K1a<<<NCH, 256, 0, stream>>>(anch, gt, info, meta, slab, N, G);
  kgtB<<<G, 256, 0, stream>>>(slab, gmax, NCH);
  K1c<<<NCH, 256, 0, stream>>>(anch, gt, gmax, meta, marr, counters, hist,
                               kf0, kf1, kb0, kb1, N, G);
  kcollect<<<128, 256, 0, stream>>>(counters, hist, meta, marr, binsel,
                                    colcnt, collected, N);
  k3_out<<<NCH, 256, 0, stream>>>(anch, gt, meta, marr, counters, binsel,
                                  colcnt, collected, out, N);
}

// Round 8
// 104.314 us; speedup vs baseline: 27.7073x; 1.0010x over previous
//
#include <hip/hip_runtime.h>
#include <cstdint>

#define RNG_PARTITIONABLE 1

// ---------------- Threefry-2x32 (exact JAX schedule) ----------------
__host__ __device__ inline void tf2x32(uint32_t k0, uint32_t k1,
                                       uint32_t x0, uint32_t x1,
                                       uint32_t& o0, uint32_t& o1) {
  const uint32_t k2 = k0 ^ k1 ^ 0x1BD11BDAu;
#define ROT(v, r) (((v) << (r)) | ((v) >> (32 - (r))))
#define R4(a,b,c,d) \
  x0 += x1; x1 = ROT(x1, a); x1 ^= x0; \
  x0 += x1; x1 = ROT(x1, b); x1 ^= x0; \
  x0 += x1; x1 = ROT(x1, c); x1 ^= x0; \
  x0 += x1; x1 = ROT(x1, d); x1 ^= x0;
  x0 += k0; x1 += k1;
  R4(13,15,26,6)   x0 += k1; x1 += k2 + 1u;
  R4(17,29,16,24)  x0 += k2; x1 += k0 + 2u;
  R4(13,15,26,6)   x0 += k0; x1 += k1 + 3u;
  R4(17,29,16,24)  x0 += k1; x1 += k2 + 4u;
  R4(13,15,26,6)   x0 += k2; x1 += k0 + 5u;
  o0 = x0; o1 = x1;
#undef R4
#undef ROT
}

// ---------------- exact (contraction-free, IEEE) IoU ----------------
__device__ __forceinline__ float iou_fn(float ax0, float ay0, float ax1, float ay1,
                                        float g0, float g1, float g2, float g3,
                                        float area_a, float area_g) {
  float ix0 = fmaxf(ax0, g0);
  float iy0 = fmaxf(ay0, g1);
  float ix1 = fminf(ax1, g2);
  float iy1 = fminf(ay1, g3);
  float iw = fmaxf(__fsub_rn(ix1, ix0), 0.0f);
  float ih = fmaxf(__fsub_rn(iy1, iy0), 0.0f);
  float inter = __fmul_rn(iw, ih);
  float denom = __fadd_rn(__fsub_rn(__fadd_rn(area_a, area_g), inter), 1e-5f);
  return __fdiv_rn(inter, denom);
}

__device__ __forceinline__ float area_fn(float x0, float y0, float x1, float y1) {
  return __fmul_rn(fmaxf(__fsub_rn(x1, x0), 0.0f), fmaxf(__fsub_rn(y1, y0), 0.0f));
}

// ---------------- kz: zero counters/colcnt/binsel/gmax/hist (132096 B) -------
__global__ void kz(int4* ws4) {
  int i = blockIdx.x * 256 + threadIdx.x;
  if (i < 8256) ws4[i] = make_int4(0, 0, 0, 0);   // 8256*16 = 132096 bytes
}

// ---------------- K1a: anchor-major; wave-bbox skip; fused per-gt slab -------
__global__ void __launch_bounds__(256) K1a(const float4* __restrict__ anch,
        const float* __restrict__ gt, const float* __restrict__ info,
        int* __restrict__ meta, float* __restrict__ slab, int N, int G) {
  __shared__ float4 sg[128];
  __shared__ float sga[128];
  __shared__ int smax[128];
  const int t = threadIdx.x;
  for (int q = t; q < G; q += 256) {
    float g0 = gt[5*q], g1 = gt[5*q+1], g2 = gt[5*q+2], g3 = gt[5*q+3];
    sg[q] = make_float4(g0, g1, g2, g3);
    sga[q] = area_fn(g0, g1, g2, g3);
    smax[q] = 0;                       // 0.0f bits (valid: true gt-max >= 0)
  }
  __syncthreads();
  const float Himg = info[0], Wimg = info[1];
  const int i = blockIdx.x * 256 + t;
  float4 a = make_float4(0.f, 0.f, 0.f, 0.f);
  bool inside = false;
  float area_a = 0.f;
  float ex0 = INFINITY, ey0 = INFINITY, ex1 = -INFINITY, ey1 = -INFINITY;
  if (i < N) {
    a = anch[i];
    inside = (a.x >= 0.f) && (a.y >= 0.f) && (a.z < Wimg) && (a.w < Himg);
    if (inside) { ex0 = a.x; ey0 = a.y; ex1 = a.z; ey1 = a.w; }
    area_a = area_fn(a.x, a.y, a.z, a.w);
  }
  // wave bbox over inside lanes (conservative superset test)
  float wx0 = ex0, wy0 = ey0, wx1 = ex1, wy1 = ey1;
  #pragma unroll
  for (int d = 32; d; d >>= 1) {
    wx0 = fminf(wx0, __shfl_xor(wx0, d));
    wy0 = fminf(wy0, __shfl_xor(wy0, d));
    wx1 = fmaxf(wx1, __shfl_xor(wx1, d));
    wy1 = fmaxf(wy1, __shfl_xor(wy1, d));
  }
  float best = inside ? 0.0f : -1.0f;  // all-zero/-1 rows: argmax = 0 (matches ref)
  int bj = 0;
  const int lane0 = ((t & 63) == 0);
  for (int j = 0; j < G; ++j) {
    // uniform-address loads (scalarizable) for the wave-level reject
    const float g0 = gt[5*j], g1 = gt[5*j+1], g2 = gt[5*j+2], g3 = gt[5*j+3];
    if (wx0 < g2 && g0 < wx1 && wy0 < g3 && g1 < wy1) {   // uniform branch
      float4 p = sg[j];
      float iou = iou_fn(a.x, a.y, a.z, a.w, p.x, p.y, p.z, p.w, area_a, sga[j]);
      float mval = inside ? iou : -1.0f;
      if (mval > best) { best = mval; bj = j; }           // strict >: FIRST argmax
      float w = mval;                                     // exact fmax reduce
      #pragma unroll
      for (int d = 32; d; d >>= 1) w = fmaxf(w, __shfl_xor(w, d));
      if (lane0) atomicMax(&smax[j], __float_as_int(w));  // w<0 int-neg < 0 init
    }
  }
  if (i < N) {
    int cls = (best < 0.3f) ? 0 : ((best >= 0.7f) ? 2 : 1);
    meta[i] = bj | (inside ? 512 : 0) | (cls << 10);
  }
  __syncthreads();
  for (int q = t; q < G; q += 256)
    slab[(size_t)blockIdx.x * 128 + q] = __int_as_float(smax[q]);
}

// ---------------- kgtB: reduce slab column -> gmax ---------------------------
__global__ void __launch_bounds__(256) kgtB(const float* __restrict__ slab,
                                            int* __restrict__ gmax, int nchunks) {
  __shared__ float red[256];
  const int t = threadIdx.x;
  const int j = blockIdx.x;
  float best = 0.0f;
  for (int c = t; c < nchunks; c += 256)
    best = fmaxf(best, slab[(size_t)c * 128 + j]);
  red[t] = best;
  __syncthreads();
  #pragma unroll
  for (int s = 128; s > 0; s >>= 1) {
    if (t < s) red[t] = fmaxf(red[t], red[t + s]);
    __syncthreads();
  }
  if (t == 0) gmax[j] = __float_as_int(red[0]);
}

// ---------------- K1c: labels (is_gt_best only for mid class) + rng + hist ---
__global__ void __launch_bounds__(256) K1c(const float4* __restrict__ anch,
        const float* __restrict__ gt, const int* __restrict__ gmax,
        int* __restrict__ meta, unsigned* __restrict__ marr,
        int* __restrict__ counters, int* __restrict__ hist,
        uint32_t kf0, uint32_t kf1, uint32_t kb0, uint32_t kb1,
        int N, int G) {
  __shared__ float4 sg[128];
  __shared__ float sga[128];
  __shared__ float sgm[128];
  __shared__ int cnt_s[2];
  __shared__ int zlist[16];
  __shared__ int zn;
  const int t = threadIdx.x;
  if (t == 0) zn = 0;
  if (t < 2) cnt_s[t] = 0;
  for (int q = t; q < G; q += 256) {
    float g0 = gt[5*q], g1 = gt[5*q+1], g2 = gt[5*q+2], g3 = gt[5*q+3];
    sg[q] = make_float4(g0, g1, g2, g3);
    sga[q] = area_fn(g0, g1, g2, g3);
    float gm = __int_as_float(gmax[q]);
    sgm[q] = gm;
    if (gm == 0.0f) { int p = atomicAdd(&zn, 1); if (p < 16) zlist[p] = q; }
  }
  __syncthreads();
  const int i = blockIdx.x * 256 + t;
  int mt = 0; bool inside = false; int cls = 0;
  float4 a = make_float4(0.f, 0.f, 0.f, 0.f);
  if (i < N) {
    mt = meta[i];
    inside = (mt >> 9) & 1;
    cls = (mt >> 10) & 3;
  }
  const bool need = (i < N) && inside && (cls == 1);
  bool gbest = false;
  if (__any(need)) {
    float area_a = 0.f;
    if (i < N) { a = anch[i]; area_a = area_fn(a.x, a.y, a.z, a.w); }
    float ex0 = need ? a.x : INFINITY,  ey0 = need ? a.y : INFINITY;
    float ex1 = need ? a.z : -INFINITY, ey1 = need ? a.w : -INFINITY;
    float wx0 = ex0, wy0 = ey0, wx1 = ex1, wy1 = ey1;
    #pragma unroll
    for (int d = 32; d; d >>= 1) {
      wx0 = fminf(wx0, __shfl_xor(wx0, d));
      wy0 = fminf(wy0, __shfl_xor(wy0, d));
      wx1 = fmaxf(wx1, __shfl_xor(wx1, d));
      wy1 = fmaxf(wy1, __shfl_xor(wy1, d));
    }
    for (int j = 0; j < G; ++j) {
      const float g0 = gt[5*j], g1 = gt[5*j+1], g2 = gt[5*j+2], g3 = gt[5*j+3];
      if (wx0 < g2 && g0 < wx1 && wy0 < g3 && g1 < wy1) {
        float4 p = sg[j];
        float iou = iou_fn(a.x, a.y, a.z, a.w, p.x, p.y, p.z, p.w, area_a, sga[j]);
        gbest = gbest | (need && (iou == sgm[j]));
      }
    }
    // exact handling of degenerate gmax==0 gts: iou==0==gmax  <=>  no overlap
    for (int z = 0; z < 16; ++z) {
      if (z >= zn) break;
      float4 p = sg[zlist[z]];
      bool ov = (a.x < p.z) && (p.x < a.z) && (a.y < p.w) && (p.y < a.w);
      gbest = gbest | (need && !ov);
    }
  }
  int lab = -1;
  if (i < N && inside)
    lab = (cls == 0) ? 0 : ((cls == 2) ? 1 : (gbest ? 1 : -1));
  unsigned long long bf = __ballot(lab == 1), bb = __ballot(lab == 0);
  if ((t & 63) == 0) {
    if (bf) atomicAdd(&cnt_s[0], __popcll(bf));
    if (bb) atomicAdd(&cnt_s[1], __popcll(bb));
  }
  __syncthreads();
  if (t == 0) {
    if (cnt_s[0]) atomicAdd(&counters[0], cnt_s[0]);
    if (cnt_s[1]) atomicAdd(&counters[1], cnt_s[1]);
  }
  if (i >= N) return;
  uint32_t Kk0 = (lab == 1) ? kf0 : kb0;
  uint32_t Kk1 = (lab == 1) ? kf1 : kb1;
  uint32_t o0, o1;
#if RNG_PARTITIONABLE
  tf2x32(Kk0, Kk1, 0u, (uint32_t)i, o0, o1);
  unsigned m = (o0 ^ o1) >> 9;
#else
  unsigned m;
  int NH = N >> 1;
  if (i < NH) { tf2x32(Kk0, Kk1, (uint32_t)i, (uint32_t)(i + NH), o0, o1); m = o0 >> 9; }
  else        { tf2x32(Kk0, Kk1, (uint32_t)(i - NH), (uint32_t)i, o0, o1); m = o1 >> 9; }
#endif
  marr[i] = m;
  meta[i] = (mt & 0xFFF) | ((lab + 1) << 12);
  if (lab >= 0) {
    int s = lab ? 0 : 1;
    unsigned long long key = ((unsigned long long)m << 19) | (unsigned)i;
    atomicAdd(&hist[s * 16384 + (int)(key >> 28)], 1);
  }
}

// ---------------- kcollect (+resolveA prologue per block) --------------------
__global__ void __launch_bounds__(256) kcollect(const int* __restrict__ counters,
        const int* __restrict__ hist, const int* __restrict__ meta,
        const unsigned* __restrict__ marr, int* __restrict__ binsel_g,
        int* __restrict__ colcnt, unsigned long long* __restrict__ collected, int N) {
  __shared__ int part[256];
  __shared__ int sbin[2], srank[2];
  __shared__ int schunk;
  const int t = threadIdx.x;
  int fgc = counters[0], bgc = counters[1];
  int fgk = min(fgc, 128);
  int Ks[2] = { fgk, min(256 - fgk, bgc) };
  for (int s = 0; s < 2; ++s) {
    int K = Ks[s];
    if (K <= 0) {                        // uniform branch
      if (t == 0) { sbin[s] = -1; srank[s] = 0; }
      __syncthreads();
      continue;
    }
    const int* h = hist + s * 16384;
    int sum = 0;
    #pragma unroll
    for (int b = 0; b < 64; ++b) sum += h[t * 64 + b];
    part[t] = sum;
    __syncthreads();
    if (t == 0) {
      int cum = 0, rch = K; schunk = 255;
      for (int q = 0; q < 256; ++q) {
        if (cum + part[q] >= K) { schunk = q; rch = K - cum; break; }
        cum += part[q];
      }
      int cum2 = 0;
      for (int b = 0; b < 64; ++b) {
        int hv = h[schunk * 64 + b];
        if (cum2 + hv >= rch) { sbin[s] = schunk * 64 + b; srank[s] = rch - cum2; break; }
        cum2 += hv;
      }
    }
    __syncthreads();
  }
  if (blockIdx.x == 0 && t < 2) { binsel_g[t] = sbin[t]; binsel_g[2 + t] = srank[t]; }
  const int b0 = sbin[0], b1 = sbin[1];
  int stride = gridDim.x * blockDim.x;
  for (int i = blockIdx.x * blockDim.x + t; i < N; i += stride) {
    int lab = ((meta[i] >> 12) & 3) - 1;
    if (lab < 0) continue;
    int s = lab ? 0 : 1;
    unsigned long long key = ((unsigned long long)marr[i] << 19) | (unsigned)i;
    if ((int)(key >> 28) != (s ? b1 : b0)) continue;
    int slot = atomicAdd(&colcnt[s], 1);
    if (slot < 1024) collected[s * 1024 + slot] = key;
  }
}

// ---------------- k3 (+resolveB prologue): final outputs ---------------------
__global__ void __launch_bounds__(256) k3_out(const float4* __restrict__ anch,
        const float* __restrict__ gt, const int* __restrict__ meta,
        const unsigned* __restrict__ marr, const int* __restrict__ counters,
        const int* __restrict__ binsel_g, const int* __restrict__ colcnt,
        const unsigned long long* __restrict__ collected,
        float* __restrict__ out, int N) {
  __shared__ unsigned long long skeys[1024];
  __shared__ unsigned long long sthr[2];
  const int t = threadIdx.x;
  int fgc = counters[0], bgc = counters[1];
  int fgk = min(fgc, 128);
  int Ks[2] = { fgk, min(256 - fgk, bgc) };
  for (int s = 0; s < 2; ++s) {
    if (Ks[s] <= 0) {                    // uniform
      if (t == 0) sthr[s] = 0ull;
      __syncthreads(); __syncthreads();
      continue;
    }
    int n = min(colcnt[s], 1024);
    int r = binsel_g[2 + s];
    for (int kk = t; kk < n; kk += 256) skeys[kk] = collected[s * 1024 + kk];
    __syncthreads();
    for (int kk = t; kk < n; kk += 256) {
      unsigned long long k = skeys[kk];
      int rank = 0;
      for (int u = 0; u < n; ++u) rank += (skeys[u] < k);
      if (rank == r - 1) sthr[s] = k + 1ull;  // keep iff key < thr
    }
    __syncthreads();
  }
  const int ne = fgk + min(256 - fgk, bgc);
  int i = blockIdx.x * blockDim.x + t;
  if (i >= N) return;
  int mt = meta[i];
  int lab = ((mt >> 12) & 3) - 1;
  bool inside = (mt >> 9) & 1;
  int am = mt & 0x1FF;
  if (lab >= 0) {
    int s = lab ? 0 : 1;
    unsigned long long key = ((unsigned long long)marr[i] << 19) | (unsigned)i;
    if (key >= sthr[s]) lab = -1;
  }
  out[i] = (float)lab;
  float4 tg = make_float4(0.0f, 0.0f, 0.0f, 0.0f);
  if (inside) {
    float4 a = anch[i];
    float g0 = gt[5*am], g1 = gt[5*am+1], g2 = gt[5*am+2], g3 = gt[5*am+3];
    float ew = __fadd_rn(__fsub_rn(a.z, a.x), 1.0f);
    float eh = __fadd_rn(__fsub_rn(a.w, a.y), 1.0f);
    float ecx = __fadd_rn(a.x, __fmul_rn(0.5f, ew));
    float ecy = __fadd_rn(a.y, __fmul_rn(0.5f, eh));
    float gw = __fadd_rn(__fsub_rn(g2, g0), 1.0f);
    float gh = __fadd_rn(__fsub_rn(g3, g1), 1.0f);
    float gcx = __fadd_rn(g0, __fmul_rn(0.5f, gw));
    float gcy = __fadd_rn(g1, __fmul_rn(0.5f, gh));
    tg = make_float4(__fdiv_rn(__fsub_rn(gcx, ecx), ew),
                     __fdiv_rn(__fsub_rn(gcy, ecy), eh),
                     logf(__fdiv_rn(gw, ew)),
                     logf(__fdiv_rn(gh, eh)));
  }
  reinterpret_cast<float4*>(out + (size_t)N)[i] = tg;
  float bw = (lab == 1) ? 1.0f : 0.0f;
  reinterpret_cast<float4*>(out + 5 * (size_t)N)[i] = make_float4(bw, bw, bw, bw);
  float ov = (lab >= 0) ? __fdiv_rn(1.0f, (float)ne) : 0.0f;
  reinterpret_cast<float4*>(out + 9 * (size_t)N)[i] = make_float4(ov, ov, ov, ov);
}

// ---------------- launch ----------------
extern "C" void kernel_launch(void* const* d_in, const int* in_sizes, int n_in,
                              void* d_out, int out_size, void* d_ws, size_t ws_size,
                              hipStream_t stream) {
  const float4* anch = (const float4*)d_in[3];
  const float* gt    = (const float*)d_in[1];
  const float* info  = (const float*)d_in[2];
  float* out = (float*)d_out;
  const int N = in_sizes[3] / 4;                 // 331776 (< 2^19 for key packing)
  const int G = in_sizes[1] / 5;                 // 128 (must be <= 128)
  const int NCH = (N + 255) / 256;               // 1296 chunks

  // workspace layout (~3.31 MB)
  char* ws = (char*)d_ws;
  int* counters = (int*)(ws + 0);                // 2 ints
  int* colcnt   = (int*)(ws + 8);                // 2 ints
  int* binsel   = (int*)(ws + 16);               // bin[2], rank[2]
  int* gmax     = (int*)(ws + 64);               // 128 ints (float bits)
  int* hist     = (int*)(ws + 1024);             // 2*16384 ints -> end 132096
  unsigned long long* collected = (unsigned long long*)(ws + 132096); // 2*1024 u64 -> 148480
  float* slab    = (float*)(ws + 148480);        // NCH*128 floats
  size_t slab_end = 148480 + (size_t)NCH * 128 * 4;
  unsigned* marr = (unsigned*)(ws + slab_end);
  int* meta      = (int*)(ws + slab_end + 4ull * (size_t)N);

  // host-side key derivation: kf, kb = split(key(42))
  uint32_t kf0, kf1, kb0, kb1;
#if RNG_PARTITIONABLE
  tf2x32(0u, 42u, 0u, 0u, kf0, kf1);
  tf2x32(0u, 42u, 0u, 1u, kb0, kb1);
#else
  {
    uint32_t a0, a1, b0, b1;
    tf2x32(0u, 42u, 0u, 2u, a0, a1);
    tf2x32(0u, 42u, 1u, 3u, b0, b1);
    kf0 = a0; kf1 = b0; kb0 = a1; kb1 = b1;
  }
#endif

  kz<<<33, 256, 0, stream>>>((int4*)ws);         // counters+colcnt+binsel+gmax+hist
  K1a<<<NCH, 256, 0, stream>>>(anch, gt, info, meta, slab, N, G);
  kgtB<<<G, 256, 0, stream>>>(slab, gmax, NCH);
  K1c<<<NCH, 256, 0, stream>>>(anch, gt, gmax, meta, marr, counters, hist,
                               kf0, kf1, kb0, kb1, N, G);
  kcollect<<<128, 256, 0, stream>>>(counters, hist, meta, marr, binsel,
                                    colcnt, collected, N);
  k3_out<<<NCH, 256, 0, stream>>>(anch, gt, meta, marr, counters, binsel,
                                  colcnt, collected, out, N);
}

// Round 9
// 72.885 us; speedup vs baseline: 39.6551x; 1.4312x over previous
//
#include <hip/hip_runtime.h>
#include <cstdint>

#define RNG_PARTITIONABLE 1

// ---------------- Threefry-2x32 (exact JAX schedule) ----------------
__host__ __device__ inline void tf2x32(uint32_t k0, uint32_t k1,
                                       uint32_t x0, uint32_t x1,
                                       uint32_t& o0, uint32_t& o1) {
  const uint32_t k2 = k0 ^ k1 ^ 0x1BD11BDAu;
#define ROT(v, r) (((v) << (r)) | ((v) >> (32 - (r))))
#define R4(a,b,c,d) \
  x0 += x1; x1 = ROT(x1, a); x1 ^= x0; \
  x0 += x1; x1 = ROT(x1, b); x1 ^= x0; \
  x0 += x1; x1 = ROT(x1, c); x1 ^= x0; \
  x0 += x1; x1 = ROT(x1, d); x1 ^= x0;
  x0 += k0; x1 += k1;
  R4(13,15,26,6)   x0 += k1; x1 += k2 + 1u;
  R4(17,29,16,24)  x0 += k2; x1 += k0 + 2u;
  R4(13,15,26,6)   x0 += k0; x1 += k1 + 3u;
  R4(17,29,16,24)  x0 += k1; x1 += k2 + 4u;
  R4(13,15,26,6)   x0 += k2; x1 += k0 + 5u;
  o0 = x0; o1 = x1;
#undef R4
#undef ROT
}

// ---------------- exact (contraction-free, IEEE) IoU ----------------
__device__ __forceinline__ float iou_fn(float ax0, float ay0, float ax1, float ay1,
                                        float g0, float g1, float g2, float g3,
                                        float area_a, float area_g) {
  float ix0 = fmaxf(ax0, g0);
  float iy0 = fmaxf(ay0, g1);
  float ix1 = fminf(ax1, g2);
  float iy1 = fminf(ay1, g3);
  float iw = fmaxf(__fsub_rn(ix1, ix0), 0.0f);
  float ih = fmaxf(__fsub_rn(iy1, iy0), 0.0f);
  float inter = __fmul_rn(iw, ih);
  float denom = __fadd_rn(__fsub_rn(__fadd_rn(area_a, area_g), inter), 1e-5f);
  return __fdiv_rn(inter, denom);
}

__device__ __forceinline__ float area_fn(float x0, float y0, float x1, float y1) {
  return __fmul_rn(fmaxf(__fsub_rn(x1, x0), 0.0f), fmaxf(__fsub_rn(y1, y0), 0.0f));
}

// ---------------- kz: zero counters/colcnt/binsel/gmax/hist (132096 B) -------
__global__ void kz(int4* ws4) {
  int i = blockIdx.x * 256 + threadIdx.x;
  if (i < 8256) ws4[i] = make_int4(0, 0, 0, 0);   // 8256*16 = 132096 bytes
}

// ---------------- K1a: anchor-major; wave pass-mask; fused per-gt slab -------
__global__ void __launch_bounds__(256) K1a(const float4* __restrict__ anch,
        const float* __restrict__ gt, const float* __restrict__ info,
        int* __restrict__ meta, float* __restrict__ slab, int N, int G) {
  __shared__ float4 sg[128];
  __shared__ int smax[128];
  const int t = threadIdx.x;
  for (int q = t; q < G; q += 256) {
    float g0 = gt[5*q], g1 = gt[5*q+1], g2 = gt[5*q+2], g3 = gt[5*q+3];
    sg[q] = make_float4(g0, g1, g2, g3);
    smax[q] = 0;                       // 0.0f bits (valid: true gt-max >= 0)
  }
  __syncthreads();
  const float Himg = info[0], Wimg = info[1];
  const int i = blockIdx.x * 256 + t;
  float4 a = make_float4(0.f, 0.f, 0.f, 0.f);
  bool inside = false;
  float area_a = 0.f;
  float ex0 = INFINITY, ey0 = INFINITY, ex1 = -INFINITY, ey1 = -INFINITY;
  if (i < N) {
    a = anch[i];
    inside = (a.x >= 0.f) && (a.y >= 0.f) && (a.z < Wimg) && (a.w < Himg);
    if (inside) { ex0 = a.x; ey0 = a.y; ex1 = a.z; ey1 = a.w; }
    area_a = area_fn(a.x, a.y, a.z, a.w);
  }
  // wave bbox over inside lanes (conservative superset test)
  float wx0 = ex0, wy0 = ey0, wx1 = ex1, wy1 = ey1;
  #pragma unroll
  for (int d = 32; d; d >>= 1) {
    wx0 = fminf(wx0, __shfl_xor(wx0, d));
    wy0 = fminf(wy0, __shfl_xor(wy0, d));
    wx1 = fmaxf(wx1, __shfl_xor(wx1, d));
    wy1 = fmaxf(wy1, __shfl_xor(wy1, d));
  }
  // wave-uniform pass masks: lane l tests gt l and gt l+64
  const int l = t & 63;
  bool p0 = false, p1 = false;
  if (l < G) {
    float4 p = sg[l];
    p0 = (wx0 < p.z) && (p.x < wx1) && (wy0 < p.w) && (p.y < wy1);
  }
  if (l + 64 < G) {
    float4 p = sg[l + 64];
    p1 = (wx0 < p.z) && (p.x < wx1) && (wy0 < p.w) && (p.y < wy1);
  }
  unsigned long long m0 = __ballot(p0);
  unsigned long long m1 = __ballot(p1);
  float best = inside ? 0.0f : -1.0f;  // all-skip rows: argmax = 0 (matches ref)
  int bj = 0;
  const int lane0 = (l == 0);
  while (m0) {                                          // j ascending in [0,64)
    int j = __ffsll((unsigned long long)m0) - 1; m0 &= m0 - 1;
    float4 p = sg[j];
    float ag = area_fn(p.x, p.y, p.z, p.w);
    float iou = iou_fn(a.x, a.y, a.z, a.w, p.x, p.y, p.z, p.w, area_a, ag);
    float mval = inside ? iou : -1.0f;
    if (mval > best) { best = mval; bj = j; }           // strict >: FIRST argmax
    float w = mval;                                     // exact fmax reduce
    #pragma unroll
    for (int d = 32; d; d >>= 1) w = fmaxf(w, __shfl_xor(w, d));
    if (lane0) atomicMax(&smax[j], __float_as_int(w));
  }
  while (m1) {                                          // then [64,128) ascending
    int j = __ffsll((unsigned long long)m1) - 1 + 64; m1 &= m1 - 1;
    float4 p = sg[j];
    float ag = area_fn(p.x, p.y, p.z, p.w);
    float iou = iou_fn(a.x, a.y, a.z, a.w, p.x, p.y, p.z, p.w, area_a, ag);
    float mval = inside ? iou : -1.0f;
    if (mval > best) { best = mval; bj = j; }
    float w = mval;
    #pragma unroll
    for (int d = 32; d; d >>= 1) w = fmaxf(w, __shfl_xor(w, d));
    if (lane0) atomicMax(&smax[j], __float_as_int(w));
  }
  if (i < N) {
    int cls = (best < 0.3f) ? 0 : ((best >= 0.7f) ? 2 : 1);
    meta[i] = bj | (inside ? 512 : 0) | (cls << 10);
  }
  __syncthreads();
  for (int q = t; q < G; q += 256)
    slab[(size_t)blockIdx.x * 128 + q] = __int_as_float(smax[q]);
}

// ---------------- kgtB: reduce slab column -> gmax ---------------------------
__global__ void __launch_bounds__(256) kgtB(const float* __restrict__ slab,
                                            int* __restrict__ gmax, int nchunks) {
  __shared__ float red[256];
  const int t = threadIdx.x;
  const int j = blockIdx.x;
  float best = 0.0f;
  for (int c = t; c < nchunks; c += 256)
    best = fmaxf(best, slab[(size_t)c * 128 + j]);
  red[t] = best;
  __syncthreads();
  #pragma unroll
  for (int s = 128; s > 0; s >>= 1) {
    if (t < s) red[t] = fmaxf(red[t], red[t + s]);
    __syncthreads();
  }
  if (t == 0) gmax[j] = __float_as_int(red[0]);
}

// ---------------- K1c: labels (is_gt_best only for mid class) + rng + hist ---
__global__ void __launch_bounds__(256) K1c(const float4* __restrict__ anch,
        const float* __restrict__ gt, const int* __restrict__ gmax,
        int* __restrict__ meta, unsigned* __restrict__ marr,
        int* __restrict__ counters, int* __restrict__ hist,
        uint32_t kf0, uint32_t kf1, uint32_t kb0, uint32_t kb1,
        int N, int G) {
  __shared__ float4 sg[128];
  __shared__ float sgm[128];
  __shared__ int cnt_s[2];
  __shared__ int zlist[16];
  __shared__ int zn;
  const int t = threadIdx.x;
  if (t == 0) zn = 0;
  if (t < 2) cnt_s[t] = 0;
  for (int q = t; q < G; q += 256) {
    float g0 = gt[5*q], g1 = gt[5*q+1], g2 = gt[5*q+2], g3 = gt[5*q+3];
    sg[q] = make_float4(g0, g1, g2, g3);
    float gm = __int_as_float(gmax[q]);
    sgm[q] = gm;
    if (gm == 0.0f) { int p = atomicAdd(&zn, 1); if (p < 16) zlist[p] = q; }
  }
  __syncthreads();
  const int i = blockIdx.x * 256 + t;
  int mt = 0; bool inside = false; int cls = 0;
  float4 a = make_float4(0.f, 0.f, 0.f, 0.f);
  if (i < N) {
    mt = meta[i];
    inside = (mt >> 9) & 1;
    cls = (mt >> 10) & 3;
  }
  const bool need = (i < N) && inside && (cls == 1);
  bool gbest = false;
  if (__any(need)) {
    float area_a = 0.f;
    if (i < N) { a = anch[i]; area_a = area_fn(a.x, a.y, a.z, a.w); }
    float ex0 = need ? a.x : INFINITY,  ey0 = need ? a.y : INFINITY;
    float ex1 = need ? a.z : -INFINITY, ey1 = need ? a.w : -INFINITY;
    float wx0 = ex0, wy0 = ey0, wx1 = ex1, wy1 = ey1;
    #pragma unroll
    for (int d = 32; d; d >>= 1) {
      wx0 = fminf(wx0, __shfl_xor(wx0, d));
      wy0 = fminf(wy0, __shfl_xor(wy0, d));
      wx1 = fmaxf(wx1, __shfl_xor(wx1, d));
      wy1 = fmaxf(wy1, __shfl_xor(wy1, d));
    }
    const int l = t & 63;
    bool p0 = false, p1 = false;
    if (l < G) {
      float4 p = sg[l];
      p0 = (wx0 < p.z) && (p.x < wx1) && (wy0 < p.w) && (p.y < wy1);
    }
    if (l + 64 < G) {
      float4 p = sg[l + 64];
      p1 = (wx0 < p.z) && (p.x < wx1) && (wy0 < p.w) && (p.y < wy1);
    }
    unsigned long long m0 = __ballot(p0);
    unsigned long long m1 = __ballot(p1);
    while (m0) {
      int j = __ffsll((unsigned long long)m0) - 1; m0 &= m0 - 1;
      float4 p = sg[j];
      float ag = area_fn(p.x, p.y, p.z, p.w);
      float iou = iou_fn(a.x, a.y, a.z, a.w, p.x, p.y, p.z, p.w, area_a, ag);
      gbest = gbest | (need && (iou == sgm[j]));
    }
    while (m1) {
      int j = __ffsll((unsigned long long)m1) - 1 + 64; m1 &= m1 - 1;
      float4 p = sg[j];
      float ag = area_fn(p.x, p.y, p.z, p.w);
      float iou = iou_fn(a.x, a.y, a.z, a.w, p.x, p.y, p.z, p.w, area_a, ag);
      gbest = gbest | (need && (iou == sgm[j]));
    }
    // exact handling of degenerate gmax==0 gts: iou==0==gmax  <=>  no overlap
    for (int z = 0; z < 16; ++z) {
      if (z >= zn) break;
      float4 p = sg[zlist[z]];
      bool ov = (a.x < p.z) && (p.x < a.z) && (a.y < p.w) && (p.y < a.w);
      gbest = gbest | (need && !ov);
    }
  }
  int lab = -1;
  if (i < N && inside)
    lab = (cls == 0) ? 0 : ((cls == 2) ? 1 : (gbest ? 1 : -1));
  unsigned long long bf = __ballot(lab == 1), bb = __ballot(lab == 0);
  if ((t & 63) == 0) {
    if (bf) atomicAdd(&cnt_s[0], __popcll(bf));
    if (bb) atomicAdd(&cnt_s[1], __popcll(bb));
  }
  __syncthreads();
  if (t == 0) {
    if (cnt_s[0]) atomicAdd(&counters[0], cnt_s[0]);
    if (cnt_s[1]) atomicAdd(&counters[1], cnt_s[1]);
  }
  if (i >= N) return;
  uint32_t Kk0 = (lab == 1) ? kf0 : kb0;
  uint32_t Kk1 = (lab == 1) ? kf1 : kb1;
  uint32_t o0, o1;
#if RNG_PARTITIONABLE
  tf2x32(Kk0, Kk1, 0u, (uint32_t)i, o0, o1);
  unsigned m = (o0 ^ o1) >> 9;
#else
  unsigned m;
  int NH = N >> 1;
  if (i < NH) { tf2x32(Kk0, Kk1, (uint32_t)i, (uint32_t)(i + NH), o0, o1); m = o0 >> 9; }
  else        { tf2x32(Kk0, Kk1, (uint32_t)(i - NH), (uint32_t)i, o0, o1); m = o1 >> 9; }
#endif
  marr[i] = m;
  meta[i] = (mt & 0xFFF) | ((lab + 1) << 12);
  if (lab >= 0) {
    int s = lab ? 0 : 1;
    unsigned long long key = ((unsigned long long)m << 19) | (unsigned)i;
    atomicAdd(&hist[s * 16384 + (int)(key >> 28)], 1);
  }
}

// ---------------- kcollect (+resolveA prologue per block) --------------------
__global__ void __launch_bounds__(256) kcollect(const int* __restrict__ counters,
        const int* __restrict__ hist, const int* __restrict__ meta,
        const unsigned* __restrict__ marr, int* __restrict__ binsel_g,
        int* __restrict__ colcnt, unsigned long long* __restrict__ collected, int N) {
  __shared__ int part[256];
  __shared__ int sbin[2], srank[2];
  __shared__ int schunk;
  const int t = threadIdx.x;
  int fgc = counters[0], bgc = counters[1];
  int fgk = min(fgc, 128);
  int Ks[2] = { fgk, min(256 - fgk, bgc) };
  for (int s = 0; s < 2; ++s) {
    int K = Ks[s];
    if (K <= 0) {                        // uniform branch
      if (t == 0) { sbin[s] = -1; srank[s] = 0; }
      __syncthreads();
      continue;
    }
    const int* h = hist + s * 16384;
    int sum = 0;
    #pragma unroll
    for (int b = 0; b < 64; ++b) sum += h[t * 64 + b];
    part[t] = sum;
    __syncthreads();
    if (t == 0) {
      int cum = 0, rch = K; schunk = 255;
      for (int q = 0; q < 256; ++q) {
        if (cum + part[q] >= K) { schunk = q; rch = K - cum; break; }
        cum += part[q];
      }
      int cum2 = 0;
      for (int b = 0; b < 64; ++b) {
        int hv = h[schunk * 64 + b];
        if (cum2 + hv >= rch) { sbin[s] = schunk * 64 + b; srank[s] = rch - cum2; break; }
        cum2 += hv;
      }
    }
    __syncthreads();
  }
  if (blockIdx.x == 0 && t < 2) { binsel_g[t] = sbin[t]; binsel_g[2 + t] = srank[t]; }
  const int b0 = sbin[0], b1 = sbin[1];
  int stride = gridDim.x * blockDim.x;
  for (int i = blockIdx.x * blockDim.x + t; i < N; i += stride) {
    int lab = ((meta[i] >> 12) & 3) - 1;
    if (lab < 0) continue;
    int s = lab ? 0 : 1;
    unsigned long long key = ((unsigned long long)marr[i] << 19) | (unsigned)i;
    if ((int)(key >> 28) != (s ? b1 : b0)) continue;
    int slot = atomicAdd(&colcnt[s], 1);
    if (slot < 1024) collected[s * 1024 + slot] = key;
  }
}

// ---------------- k3 (+resolveB prologue): final outputs ---------------------
__global__ void __launch_bounds__(256) k3_out(const float4* __restrict__ anch,
        const float* __restrict__ gt, const int* __restrict__ meta,
        const unsigned* __restrict__ marr, const int* __restrict__ counters,
        const int* __restrict__ binsel_g, const int* __restrict__ colcnt,
        const unsigned long long* __restrict__ collected,
        float* __restrict__ out, int N) {
  __shared__ unsigned long long skeys[1024];
  __shared__ unsigned long long sthr[2];
  const int t = threadIdx.x;
  int fgc = counters[0], bgc = counters[1];
  int fgk = min(fgc, 128);
  int Ks[2] = { fgk, min(256 - fgk, bgc) };
  for (int s = 0; s < 2; ++s) {
    if (Ks[s] <= 0) {                    // uniform
      if (t == 0) sthr[s] = 0ull;
      __syncthreads(); __syncthreads();
      continue;
    }
    int n = min(colcnt[s], 1024);
    int r = binsel_g[2 + s];
    for (int kk = t; kk < n; kk += 256) skeys[kk] = collected[s * 1024 + kk];
    __syncthreads();
    for (int kk = t; kk < n; kk += 256) {
      unsigned long long k = skeys[kk];
      int rank = 0;
      for (int u = 0; u < n; ++u) rank += (skeys[u] < k);
      if (rank == r - 1) sthr[s] = k + 1ull;  // keep iff key < thr
    }
    __syncthreads();
  }
  const int ne = fgk + min(256 - fgk, bgc);
  int i = blockIdx.x * blockDim.x + t;
  if (i >= N) return;
  int mt = meta[i];
  int lab = ((mt >> 12) & 3) - 1;
  bool inside = (mt >> 9) & 1;
  int am = mt & 0x1FF;
  if (lab >= 0) {
    int s = lab ? 0 : 1;
    unsigned long long key = ((unsigned long long)marr[i] << 19) | (unsigned)i;
    if (key >= sthr[s]) lab = -1;
  }
  out[i] = (float)lab;
  float4 tg = make_float4(0.0f, 0.0f, 0.0f, 0.0f);
  if (inside) {
    float4 a = anch[i];
    float g0 = gt[5*am], g1 = gt[5*am+1], g2 = gt[5*am+2], g3 = gt[5*am+3];
    float ew = __fadd_rn(__fsub_rn(a.z, a.x), 1.0f);
    float eh = __fadd_rn(__fsub_rn(a.w, a.y), 1.0f);
    float ecx = __fadd_rn(a.x, __fmul_rn(0.5f, ew));
    float ecy = __fadd_rn(a.y, __fmul_rn(0.5f, eh));
    float gw = __fadd_rn(__fsub_rn(g2, g0), 1.0f);
    float gh = __fadd_rn(__fsub_rn(g3, g1), 1.0f);
    float gcx = __fadd_rn(g0, __fmul_rn(0.5f, gw));
    float gcy = __fadd_rn(g1, __fmul_rn(0.5f, gh));
    tg = make_float4(__fdiv_rn(__fsub_rn(gcx, ecx), ew),
                     __fdiv_rn(__fsub_rn(gcy, ecy), eh),
                     logf(__fdiv_rn(gw, ew)),
                     logf(__fdiv_rn(gh, eh)));
  }
  reinterpret_cast<float4*>(out + (size_t)N)[i] = tg;
  float bw = (lab == 1) ? 1.0f : 0.0f;
  reinterpret_cast<float4*>(out + 5 * (size_t)N)[i] = make_float4(bw, bw, bw, bw);
  float ov = (lab >= 0) ? __fdiv_rn(1.0f, (float)ne) : 0.0f;
  reinterpret_cast<float4*>(out + 9 * (size_t)N)[i] = make_float4(ov, ov, ov, ov);
}

// ---------------- launch ----------------
extern "C" void kernel_launch(void* const* d_in, const int* in_sizes, int n_in,
                              void* d_out, int out_size, void* d_ws, size_t ws_size,
                              hipStream_t stream) {
  const float4* anch = (const float4*)d_in[3];
  const float* gt    = (const float*)d_in[1];
  const float* info  = (const float*)d_in[2];
  float* out = (float*)d_out;
  const int N = in_sizes[3] / 4;                 // 331776 (< 2^19 for key packing)
  const int G = in_sizes[1] / 5;                 // 128 (must be <= 128)
  const int NCH = (N + 255) / 256;               // 1296 chunks

  // workspace layout (~3.31 MB)
  char* ws = (char*)d_ws;
  int* counters = (int*)(ws + 0);                // 2 ints
  int* colcnt   = (int*)(ws + 8);                // 2 ints
  int* binsel   = (int*)(ws + 16);               // bin[2], rank[2]
  int* gmax     = (int*)(ws + 64);               // 128 ints (float bits)
  int* hist     = (int*)(ws + 1024);             // 2*16384 ints -> end 132096
  unsigned long long* collected = (unsigned long long*)(ws + 132096); // 2*1024 u64 -> 148480
  float* slab    = (float*)(ws + 148480);        // NCH*128 floats
  size_t slab_end = 148480 + (size_t)NCH * 128 * 4;
  unsigned* marr = (unsigned*)(ws + slab_end);
  int* meta      = (int*)(ws + slab_end + 4ull * (size_t)N);

  // host-side key derivation: kf, kb = split(key(42))
  uint32_t kf0, kf1, kb0, kb1;
#if RNG_PARTITIONABLE
  tf2x32(0u, 42u, 0u, 0u, kf0, kf1);
  tf2x32(0u, 42u, 0u, 1u, kb0, kb1);
#else
  {
    uint32_t a0, a1, b0, b1;
    tf2x32(0u, 42u, 0u, 2u, a0, a1);
    tf2x32(0u, 42u, 1u, 3u, b0, b1);
    kf0 = a0; kf1 = b0; kb0 = a1; kb1 = b1;
  }
#endif

  kz<<<33, 256, 0, stream>>>((int4*)ws);         // counters+colcnt+binsel+gmax+hist
  K1a<<<NCH, 256, 0, stream>>>(anch, gt, info, meta, slab, N, G);
  kgtB<<<G, 256, 0, stream>>>(slab, gmax, NCH);
  K1c<<<NCH, 256, 0, stream>>>(anch, gt, gmax, meta, marr, counters, hist,
                               kf0, kf1, kb0, kb1, N, G);
  kcollect<<<128, 256, 0, stream>>>(counters, hist, meta, marr, binsel,
                                    colcnt, collected, N);
  k3_out<<<NCH, 256, 0, stream>>>(anch, gt, meta, marr, counters, binsel,
                                  colcnt, collected, out, N);
}